// Round 12
// baseline (596.041 us; speedup 1.0000x reference)
//
#include <hip/hip_runtime.h>
#include <hip/hip_bf16.h>

#define NN    50000
#define RR    8
#define HIDC  128
#define NHEADS 4
#define EE    640000
#define EE2   200000
#define NCL   8

typedef __hip_bfloat16 bf16;
typedef unsigned short u16;
typedef __attribute__((ext_vector_type(8))) short short8;
typedef __attribute__((ext_vector_type(4))) float floatx4;

__device__ __forceinline__ float us2f(u16 u) {
    return __uint_as_float(((unsigned)u) << 16);
}
__device__ __forceinline__ float bf2f(bf16 v) { return __bfloat162float(v); }
__device__ __forceinline__ u16 f2us(float f) {
    bf16 h = __float2bfloat16(f);
    return *(u16*)&h;
}
__device__ __forceinline__ float ldf(const void* p, int i, bool f32) {
    return f32 ? ((const float*)p)[i] : us2f(((const u16*)p)[i]);
}
__device__ __forceinline__ float wredmax(float v) {
#pragma unroll
    for (int off = 32; off; off >>= 1) v = fmaxf(v, __shfl_xor(v, off));
    return v;
}
__device__ __forceinline__ float wredsum(float v) {
#pragma unroll
    for (int off = 32; off; off >>= 1) v += __shfl_xor(v, off);
    return v;
}

// ---------------- dtype sniff: fp32 data viewed as bf16 has exp==0xFF hits ----------------
__global__ __launch_bounds__(1024) void k_sniff(const u16* __restrict__ x, int* __restrict__ flags) {
    __shared__ int cnt;
    if (threadIdx.x == 0) cnt = 0;
    __syncthreads();
    int c = 0;
#pragma unroll
    for (int it = 0; it < 8; it++) {
        ushort4 a = ((const ushort4*)x)[(it * 1024 + threadIdx.x) * 2];
        ushort4 b = ((const ushort4*)x)[(it * 1024 + threadIdx.x) * 2 + 1];
        c += (((a.x >> 7) & 0xFF) == 0xFF) + (((a.y >> 7) & 0xFF) == 0xFF)
           + (((a.z >> 7) & 0xFF) == 0xFF) + (((a.w >> 7) & 0xFF) == 0xFF)
           + (((b.x >> 7) & 0xFF) == 0xFF) + (((b.y >> 7) & 0xFF) == 0xFF)
           + (((b.z >> 7) & 0xFF) == 0xFF) + (((b.w >> 7) & 0xFF) == 0xFF);
    }
    c += __shfl_xor(c, 32); c += __shfl_xor(c, 16); c += __shfl_xor(c, 8);
    c += __shfl_xor(c, 4);  c += __shfl_xor(c, 2);  c += __shfl_xor(c, 1);
    if ((threadIdx.x & 63) == 0) atomicAdd(&cnt, c);
    __syncthreads();
    if (threadIdx.x == 0) { flags[0] = (cnt > 16) ? 1 : 0; flags[1] = 1; }
}

// ---------------- CSR build ----------------
__global__ void k_zero(int* __restrict__ p, int n) {
    int i = blockIdx.x * 256 + threadIdx.x;
    if (i < n) p[i] = 0;
}
__global__ void k_hist(const int* __restrict__ ei, int* __restrict__ deg) {
    int e = blockIdx.x * 256 + threadIdx.x;
    if (e < EE) atomicAdd(&deg[ei[EE + e]], 1);
}
// 3-phase parallel scan
__global__ __launch_bounds__(256) void k_scan1(const int* __restrict__ deg,
                                               int* __restrict__ bsum) {
    int i = blockIdx.x * 256 + threadIdx.x;
    int v = (i < NN) ? deg[i] : 0;
    __shared__ int red[4];
    int lane = threadIdx.x & 63, w = threadIdx.x >> 6;
#pragma unroll
    for (int off = 32; off; off >>= 1) v += __shfl_xor(v, off);
    if (lane == 0) red[w] = v;
    __syncthreads();
    if (threadIdx.x == 0) bsum[blockIdx.x] = red[0] + red[1] + red[2] + red[3];
}
__global__ __launch_bounds__(256) void k_scan2(const int* __restrict__ bsum,
                                               int* __restrict__ boff,
                                               int* __restrict__ rowptr) {
    __shared__ int s[256];
    int t = threadIdx.x;
    s[t] = (t < 196) ? bsum[t] : 0;
    __syncthreads();
    for (int off = 1; off < 256; off <<= 1) {
        int u = (t >= off) ? s[t - off] : 0;
        __syncthreads();
        s[t] += u;
        __syncthreads();
    }
    if (t < 196) boff[t] = (t == 0) ? 0 : s[t - 1];
    if (t == 255) rowptr[NN] = s[255];
}
__global__ __launch_bounds__(256) void k_scan3(int* __restrict__ deg /*in deg, out cursor*/,
                                               const int* __restrict__ boff,
                                               int* __restrict__ rowptr) {
    __shared__ int s[256];
    int t = threadIdx.x;
    int i = blockIdx.x * 256 + t;
    int v = (i < NN) ? deg[i] : 0;
    s[t] = v;
    __syncthreads();
    for (int off = 1; off < 256; off <<= 1) {
        int u = (t >= off) ? s[t - off] : 0;
        __syncthreads();
        s[t] += u;
        __syncthreads();
    }
    if (i < NN) {
        int val = boff[blockIdx.x] + s[t] - v;  // exclusive
        rowptr[i] = val;
        deg[i] = val;  // cursor copy
    }
}
__global__ void k_scatter(const int* __restrict__ ei, int* __restrict__ cursor,
                          int* __restrict__ elist) {
    int e = blockIdx.x * 256 + threadIdx.x;
    if (e >= EE) return;
    int pos = atomicAdd(&cursor[ei[EE + e]], 1);
    elist[pos] = e;
}

// ---------------- qkw[mat][i][h8] = sum_o W[r][i][o] * (q|k)[o][h] ----------------
__global__ void k_qkw(const void* __restrict__ w1, const void* __restrict__ w2,
                      const void* __restrict__ q1, const void* __restrict__ k1,
                      const void* __restrict__ q2, const void* __restrict__ k2,
                      float* __restrict__ qkw, const int* __restrict__ fl) {
    int idx = blockIdx.x * 256 + threadIdx.x;  // 16*128*8 = 16384
    if (idx >= 16384) return;
    const bool f = fl[0] != 0;
    int mat = idx >> 10;
    int i   = (idx >> 3) & 127;
    int h8  = idx & 7;
    const void* W = (mat >= 8) ? w2 : w1;
    const void* qk = (mat >= 8) ? ((h8 < 4) ? q2 : k2) : ((h8 < 4) ? q1 : k1);
    int h = h8 & 3;
    int r = mat & 7;
    float acc = 0.f;
    for (int o = 0; o < HIDC; o++)
        acc += ldf(W, (r * HIDC + i) * HIDC + o, f) * ldf(qk, o * NHEADS + h, f);
    qkw[idx] = acc;
}

// ---------------- W (+qkw cols) -> MFMA B-fragment order: 9 col-tiles ----------------
__global__ void k_wswz(const void* __restrict__ w1, const void* __restrict__ w2,
                       const float* __restrict__ qkw,
                       u16* __restrict__ Wf2, const int* __restrict__ fl) {
    int idx = blockIdx.x * 256 + threadIdx.x;  // 16 * 2304 = 36864
    if (idx >= 36864) return;
    const bool f = fl[0] != 0;
    int mat = idx / 2304, rest = idx % 2304;
    int c = rest >> 8, q = (rest >> 6) & 3, ln = rest & 63;
    int k0 = q * 32 + (ln >> 4) * 8;
    int nn = c * 16 + (ln & 15);
    int r = mat & 7;
    u16 o[8];
    if (c < 8) {
        const void* W = (mat >= 8) ? w2 : w1;
#pragma unroll
        for (int j = 0; j < 8; j++)
            o[j] = f2us(ldf(W, (r * HIDC + k0 + j) * HIDC + nn, f));
    } else {
        int col = nn - 128;  // 0..15
#pragma unroll
        for (int j = 0; j < 8; j++)
            o[j] = (col < 8) ? f2us(qkw[mat * 1024 + (k0 + j) * 8 + col]) : (u16)0;
    }
    u16* dst = Wf2 + (size_t)mat * 18432 + (size_t)(((c * 4 + q) * 64 + ln) * 8);
    *(ushort4*)dst       = ushort4{o[0], o[1], o[2], o[3]};
    *(ushort4*)(dst + 4) = ushort4{o[4], o[5], o[6], o[7]};
}

// ---------------- MFMA xw + s/t from col-tile 8 ----------------
__global__ __launch_bounds__(256) void k_xw2(const void* __restrict__ X,
                                             const u16* __restrict__ Wf2,
                                             bf16* __restrict__ xw,
                                             float* __restrict__ sbuf,
                                             float* __restrict__ tbuf,
                                             const int* __restrict__ fx,
                                             int layer) {
    __shared__ u16 Xs[64 * 136];    // 17.4 KB bf16 input tile
    __shared__ float Os[64 * 132];  // 33.8 KB fp32 output tile
    const int tid = threadIdx.x;
    const int r = blockIdx.y;
    const int n0 = blockIdx.x * 64;
    const bool xf = fx[0] != 0;
    for (int v = tid; v < 2048; v += 256) {
        int row = v >> 5, c4 = (v & 31) * 4, n = n0 + row;
        ushort4 o = {0, 0, 0, 0};
        if (n < NN) {
            if (xf) {
                float4 hv = *(const float4*)((const float*)X + (size_t)n * HIDC + c4);
                o = ushort4{f2us(hv.x), f2us(hv.y), f2us(hv.z), f2us(hv.w)};
            } else {
                o = *(const ushort4*)((const u16*)X + (size_t)n * HIDC + c4);
            }
        }
        *(ushort4*)&Xs[row * 136 + c4] = o;
    }
    __syncthreads();
    const int w = tid >> 6, lane = tid & 63;
    short8 af[4];
#pragma unroll
    for (int q = 0; q < 4; q++)
        af[q] = *(const short8*)&Xs[(16 * w + (lane & 15)) * 136 + q * 32 + (lane >> 4) * 8];
    const u16* Wfr = Wf2 + (size_t)(layer * 8 + r) * 18432;
#pragma unroll
    for (int c = 0; c < 9; c++) {
        floatx4 acc = {0.f, 0.f, 0.f, 0.f};
#pragma unroll
        for (int q = 0; q < 4; q++) {
            short8 bfr = *(const short8*)&Wfr[(size_t)(((c * 4 + q) * 64 + lane) * 8)];
            acc = __builtin_amdgcn_mfma_f32_16x16x32_bf16(af[q], bfr, acc, 0, 0, 0);
        }
        if (c < 8) {
            int col = c * 16 + (lane & 15);
#pragma unroll
            for (int reg = 0; reg < 4; reg++) {
                int p = 16 * w + (lane >> 4) * 4 + reg;
                Os[p * 132 + col] = acc[reg];
            }
        } else {
            int cl = lane & 15;  // 0..3 -> s heads, 4..7 -> t heads
            if (cl < 8) {
                float* dstp = (cl < 4) ? sbuf : tbuf;
                int h = cl & 3;
#pragma unroll
                for (int reg = 0; reg < 4; reg++) {
                    int p = 16 * w + (lane >> 4) * 4 + reg;
                    int n = n0 + p;
                    if (n < NN) dstp[(size_t)(n * RR + r) * 4 + h] = acc[reg];
                }
            }
        }
    }
    __syncthreads();
    for (int v = tid; v < 2048; v += 256) {
        int row = v >> 5, c4 = (v & 31) * 4, n = n0 + row;
        if (n < NN) {
            float4 hv = *(const float4*)&Os[row * 132 + c4];
            ushort4 o = {f2us(hv.x), f2us(hv.y), f2us(hv.z), f2us(hv.w)};
            *(ushort4*)((u16*)xw + (size_t)(n * RR + r) * HIDC + c4) = o;
        }
    }
}

// ---------------- fused attention (4-edge-parallel gather) ----------------
// wave per dst; lane = (g,l): g=lane>>4 edge subgroup, l=lane&15 covers channels l*8..l*8+7
__global__ __launch_bounds__(256) void k_attn(const int* __restrict__ rowptr,
                                              const int* __restrict__ elist,
                                              const int* __restrict__ ei,
                                              const int* __restrict__ et,
                                              const float* __restrict__ sb,
                                              const float* __restrict__ tb,
                                              const bf16* __restrict__ xw,
                                              const void* __restrict__ b,
                                              const void* __restrict__ g,
                                              const void* __restrict__ bb,
                                              const float* __restrict__ hprev,
                                              float* __restrict__ hout,
                                              const int* __restrict__ fl) {
    __shared__ float ews[4][64 * 4];
    __shared__ int srs[4][64];
    const int tid = threadIdx.x;
    const int lane = tid & 63;
    const int w = tid >> 6;
    const int d = blockIdx.x * 4 + w;
    if (d >= NN) return;
    const bool f = fl[0] != 0;
    const int l = lane & 15;   // channel group (8 ch)
    const int gg = lane >> 4;  // edge subgroup
    const int hh = l >> 2;     // head of my channels
    const int start = rowptr[d], end = rowptr[d + 1];
    float m0 = -1e30f, m1 = -1e30f, m2 = -1e30f, m3 = -1e30f;
    float l0 = 0.f, l1 = 0.f, l2 = 0.f, l3 = 0.f;
    float acc[8] = {};
    for (int c0 = start; c0 < end; c0 += 64) {
        int n = end - c0;
        if (n > 64) n = 64;
        float a0, a1, a2, a3;
        int sr = 0;
        if (lane < n) {
            int e = elist[c0 + lane];
            int src = ei[e], r = et[e];
            sr = src * RR + r;
            float4 si = *(const float4*)&sb[(size_t)(d * RR + r) * 4];
            float4 tj = *(const float4*)&tb[(size_t)sr * 4];
            a0 = si.x + tj.x; a0 = a0 >= 0.f ? a0 : 0.2f * a0;
            a1 = si.y + tj.y; a1 = a1 >= 0.f ? a1 : 0.2f * a1;
            a2 = si.z + tj.z; a2 = a2 >= 0.f ? a2 : 0.2f * a2;
            a3 = si.w + tj.w; a3 = a3 >= 0.f ? a3 : 0.2f * a3;
        } else { a0 = a1 = a2 = a3 = -1e30f; }
        float n0 = fmaxf(m0, wredmax(a0));
        float n1 = fmaxf(m1, wredmax(a1));
        float n2 = fmaxf(m2, wredmax(a2));
        float n3 = fmaxf(m3, wredmax(a3));
        float s0 = __expf(m0 - n0), s1 = __expf(m1 - n1);
        float s2 = __expf(m2 - n2), s3 = __expf(m3 - n3);
        float e0 = __expf(a0 - n0), e1 = __expf(a1 - n1);
        float e2 = __expf(a2 - n2), e3 = __expf(a3 - n3);
        l0 = l0 * s0 + wredsum(e0);
        l1 = l1 * s1 + wredsum(e1);
        l2 = l2 * s2 + wredsum(e2);
        l3 = l3 * s3 + wredsum(e3);
        // stash per-edge weights + rows in wave-local LDS (no barrier needed)
        *(float4*)&ews[w][lane * 4] = float4{e0, e1, e2, e3};
        srs[w][lane] = sr;
        float scl = hh == 0 ? s0 : hh == 1 ? s1 : hh == 2 ? s2 : s3;
#pragma unroll
        for (int i = 0; i < 8; i++) acc[i] *= scl;
        // 4 edges in flight: subgroup gg takes edges gg, gg+4, gg+8, ...
        for (int el = gg; el < n; el += 4) {
            float wv = ews[w][el * 4 + hh];
            int row = srs[w][el];
            const u16* p = (const u16*)xw + (size_t)row * HIDC + l * 8;
            ushort4 ua = *(const ushort4*)p;
            ushort4 ub = *(const ushort4*)(p + 4);
            acc[0] += wv * us2f(ua.x); acc[1] += wv * us2f(ua.y);
            acc[2] += wv * us2f(ua.z); acc[3] += wv * us2f(ua.w);
            acc[4] += wv * us2f(ub.x); acc[5] += wv * us2f(ub.y);
            acc[6] += wv * us2f(ub.z); acc[7] += wv * us2f(ub.w);
        }
        m0 = n0; m1 = n1; m2 = n2; m3 = n3;
    }
    // combine the 4 edge subgroups
#pragma unroll
    for (int i = 0; i < 8; i++) {
        acc[i] += __shfl_xor(acc[i], 16);
        acc[i] += __shfl_xor(acc[i], 32);
    }
    float ld = hh == 0 ? l0 : hh == 1 ? l1 : hh == 2 ? l2 : l3;
    float inv = 1.f / (ld + 1e-16f);
    float v[8];
#pragma unroll
    for (int i = 0; i < 8; i++)
        v[i] = fmaxf(acc[i] * inv + ldf(b, l * 8 + i, f), 0.f);
    float sum = 0.f;
#pragma unroll
    for (int i = 0; i < 8; i++) sum += v[i];
#pragma unroll
    for (int off = 8; off; off >>= 1) sum += __shfl_xor(sum, off);
    float mean = sum * (1.f / 128.f);
    float sq = 0.f;
#pragma unroll
    for (int i = 0; i < 8; i++) { v[i] -= mean; sq += v[i] * v[i]; }
#pragma unroll
    for (int off = 8; off; off >>= 1) sq += __shfl_xor(sq, off);
    float rstd = rsqrtf(sq * (1.f / 128.f) + 1e-5f);
    if (gg == 0) {
        float y[8];
#pragma unroll
        for (int i = 0; i < 8; i++)
            y[i] = v[i] * rstd * ldf(g, l * 8 + i, f) + ldf(bb, l * 8 + i, f);
        if (hprev) {
            float4 ha = *(const float4*)&hprev[(size_t)d * HIDC + l * 8];
            float4 hb = *(const float4*)&hprev[(size_t)d * HIDC + l * 8 + 4];
            y[0] += ha.x; y[1] += ha.y; y[2] += ha.z; y[3] += ha.w;
            y[4] += hb.x; y[5] += hb.y; y[6] += hb.z; y[7] += hb.w;
        }
        *(float4*)&hout[(size_t)d * HIDC + l * 8]     = float4{y[0], y[1], y[2], y[3]};
        *(float4*)&hout[(size_t)d * HIDC + l * 8 + 4] = float4{y[4], y[5], y[6], y[7]};
    }
}

// ---------------- mw1 + mw2 -> B-fragment order (bf16) for MFMA decode ----------------
__global__ void k_dswz(const void* __restrict__ mw1, const void* __restrict__ mw2,
                       u16* __restrict__ Wf, const int* __restrict__ fl) {
    int idx = blockIdx.x * 256 + threadIdx.x;  // 0..4351
    if (idx >= 4352) return;
    const bool f = fl[0] != 0;
    u16 o[8];
    if (idx < 4096) {
        int c = idx >> 9, q = (idx >> 6) & 7, ln = idx & 63;
        int k0 = q * 32 + (ln >> 4) * 8;
        int nn = c * 16 + (ln & 15);
#pragma unroll
        for (int j = 0; j < 8; j++)
            o[j] = f2us(ldf(mw1, (k0 + j) * HIDC + nn, f));
    } else {
        int fidx = idx - 4096;           // q*64 + lane
        int q = fidx >> 6, ln = fidx & 63;
        int k0 = q * 32 + (ln >> 4) * 8;
        int nn = ln & 15;
#pragma unroll
        for (int j = 0; j < 8; j++)
            o[j] = (nn < 8) ? f2us(ldf(mw2, (k0 + j) * NCL + nn, f)) : (u16)0;
    }
    *(ushort4*)&Wf[idx * 8]     = ushort4{o[0], o[1], o[2], o[3]};
    *(ushort4*)&Wf[idx * 8 + 4] = ushort4{o[4], o[5], o[6], o[7]};
}

// ---------------- decode: barrier-free, direct global A-fragment gathers ----------------
__global__ __launch_bounds__(256) void k_decode2(const float* __restrict__ h,
                                                 const int* __restrict__ edges,
                                                 const u16* __restrict__ Wf,
                                                 const void* __restrict__ mb1,
                                                 const void* __restrict__ mb2,
                                                 void* __restrict__ out,
                                                 const int* __restrict__ fl) {
    __shared__ u16 zsu[64 * 136];   // 17.4 KB, wave-local rows only
    const int tid = threadIdx.x;
    const bool f = fl[0] != 0;
    const int p0 = blockIdx.x * 64;
    const int w = tid >> 6, lane = tid & 63;
    const int m = 16 * w + (lane & 15);   // row in 64-tile
    const int g = lane >> 4;              // k-group 0..3
    const int na = edges[(size_t)(p0 + m) * 2];
    const int nb = edges[(size_t)(p0 + m) * 2 + 1];
    short8 af[8];
#pragma unroll
    for (int q = 0; q < 8; q++) {
        int k0 = q * 32 + g * 8;          // 0..248
        const float* src = h + (size_t)((k0 >> 7) ? nb : na) * HIDC + (k0 & 127);
        float4 a = *(const float4*)src;
        float4 bq = *(const float4*)(src + 4);
        u16 tmp[8] = {f2us(a.x), f2us(a.y), f2us(a.z), f2us(a.w),
                      f2us(bq.x), f2us(bq.y), f2us(bq.z), f2us(bq.w)};
        af[q] = *(short8*)tmp;
    }
#pragma unroll
    for (int c = 0; c < 8; c++) {
        floatx4 acc = {0.f, 0.f, 0.f, 0.f};
#pragma unroll
        for (int q = 0; q < 8; q++) {
            short8 bfr = *(const short8*)&Wf[(size_t)(((c * 8 + q) * 64 + lane) * 8)];
            acc = __builtin_amdgcn_mfma_f32_16x16x32_bf16(af[q], bfr, acc, 0, 0, 0);
        }
        int col = c * 16 + (lane & 15);
        float bv = ldf(mb1, col, f);
#pragma unroll
        for (int reg = 0; reg < 4; reg++) {
            int p = 16 * w + (lane >> 4) * 4 + reg;
            float z = acc[reg] + bv;
            zsu[p * 136 + col] = f2us(0.5f * z * (1.f + erff(z * 0.70710678118654752f)));
        }
    }
    // second GEMM: rows wave-local -> no barrier
    floatx4 acc2 = {0.f, 0.f, 0.f, 0.f};
#pragma unroll
    for (int q = 0; q < 4; q++) {
        short8 af2 = *(const short8*)&zsu[m * 136 + q * 32 + g * 8];
        short8 bfr2 = *(const short8*)&Wf[32768 + (size_t)((q * 64 + lane) * 8)];
        acc2 = __builtin_amdgcn_mfma_f32_16x16x32_bf16(af2, bfr2, acc2, 0, 0, 0);
    }
    int col16 = lane & 15;
    if (col16 < 8) {
        float bv2 = ldf(mb2, col16, f);
#pragma unroll
        for (int reg = 0; reg < 4; reg++) {
            int p = 16 * w + (lane >> 4) * 4 + reg;
            float sv = acc2[reg] + bv2;
            size_t oi = (size_t)(p0 + p) * NCL + col16;
            if (f) ((float*)out)[oi] = sv;
            else   ((bf16*)out)[oi] = __float2bfloat16(sv);
        }
    }
}

extern "C" void kernel_launch(void* const* d_in, const int* in_sizes, int n_in,
                              void* d_out, int out_size, void* d_ws, size_t ws_size,
                              hipStream_t stream) {
    (void)in_sizes; (void)n_in; (void)out_size; (void)ws_size;
    const void* x    = d_in[0];
    const int* ei    = (const int*)d_in[1];
    const int* et    = (const int*)d_in[2];
    const int* edges = (const int*)d_in[3];
    const void* w1 = d_in[4];
    const void* q1 = d_in[5];
    const void* k1 = d_in[6];
    const void* b1 = d_in[7];
    const void* w2 = d_in[8];
    const void* q2 = d_in[9];
    const void* k2 = d_in[10];
    const void* b2 = d_in[11];
    const void* ln1g = d_in[12];
    const void* ln1b = d_in[13];
    const void* ln2g = d_in[14];
    const void* ln2b = d_in[15];
    const void* mw1 = d_in[16];
    const void* mb1 = d_in[17];
    const void* mw2 = d_in[18];
    const void* mb2 = d_in[19];

    // workspace layout — within round-3-proven bound (<= 169,425,560 B)
    char* ws = (char*)d_ws;
    bf16* xwb   = (bf16*)ws;                      // [0, 102,400,000)
    u16* Wf     = (u16*)ws;                       // ALIAS xwb: k_dswz runs after last xwb read (69,632 B)
    float* sbuf = (float*)(ws + 102400000);       // 6.4 MB
    float* tbuf = (float*)(ws + 108800000);       // 6.4 MB
    float* h1   = (float*)(ws + 115200000);       // 25.6 MB
    float* hsum = (float*)(ws + 140800000);       // 25.6 MB
    u16* Wf2    = (u16*)(ws + 140800000);         // ALIAS hsum: dead before hsum is written (589,824 B)
    int* rowptr = (int*)(ws + 166400000);         // NN+1 ints
    int* cursor = (int*)(ws + 166600016);         // NN ints
    int* elist  = (int*)(ws + 166800016);         // EE ints
    float* qkw  = (float*)(ws + 169360016);       // 65,536 B -> ends 169,425,552
    int* bsum   = (int*)qkw;                      // ALIAS qkw: scan phases finish before k_qkw writes
    int* boff   = bsum + 256;
    int* flags  = (int*)(ws + 169425552);         // 8 B -> ends 169,425,560 (proven)

    k_sniff<<<1, 1024, 0, stream>>>((const u16*)x, flags);

    // CSR build (parallel 3-phase scan) + weight preprocessing
    k_zero<<<196, 256, 0, stream>>>(cursor, NN);
    k_hist<<<2500, 256, 0, stream>>>(ei, cursor);
    k_scan1<<<196, 256, 0, stream>>>(cursor, bsum);
    k_scan2<<<1, 256, 0, stream>>>(bsum, boff, rowptr);
    k_scan3<<<196, 256, 0, stream>>>(cursor, boff, rowptr);
    k_scatter<<<2500, 256, 0, stream>>>(ei, cursor, elist);
    k_qkw<<<64, 256, 0, stream>>>(w1, w2, q1, k1, q2, k2, qkw, flags);
    k_wswz<<<144, 256, 0, stream>>>(w1, w2, qkw, Wf2, flags);

    for (int layer = 0; layer < 2; ++layer) {
        const void* b  = layer ? b2 : b1;
        const void* lg = layer ? ln2g : ln1g;
        const void* lb = layer ? ln2b : ln1b;
        k_xw2<<<dim3(782, 8), 256, 0, stream>>>(layer ? (const void*)h1 : x, Wf2, xwb,
                                                sbuf, tbuf,
                                                layer ? flags + 1 : flags, layer);
        k_attn<<<12500, 256, 0, stream>>>(rowptr, elist, ei, et, sbuf, tbuf, xwb,
                                          b, lg, lb,
                                          layer ? h1 : (const float*)nullptr,
                                          layer ? hsum : h1, flags);
    }
    // decode weight swizzle into xwb space (xwb dead after attn L1)
    k_dswz<<<17, 256, 0, stream>>>(mw1, mw2, Wf, flags);
    k_decode2<<<3125, 256, 0, stream>>>(hsum, edges, Wf, mb1, mb2, d_out, flags);
}

// Round 13
// 533.423 us; speedup vs baseline: 1.1174x; 1.1174x over previous
//
#include <hip/hip_runtime.h>
#include <hip/hip_bf16.h>

#define NN    50000
#define RR    8
#define HIDC  128
#define NHEADS 4
#define EE    640000
#define EE2   200000
#define NCL   8

typedef __hip_bfloat16 bf16;
typedef unsigned short u16;
typedef __attribute__((ext_vector_type(8))) short short8;
typedef __attribute__((ext_vector_type(4))) float floatx4;

__device__ __forceinline__ float us2f(u16 u) {
    return __uint_as_float(((unsigned)u) << 16);
}
__device__ __forceinline__ float bf2f(bf16 v) { return __bfloat162float(v); }
__device__ __forceinline__ u16 f2us(float f) {
    bf16 h = __float2bfloat16(f);
    return *(u16*)&h;
}
__device__ __forceinline__ float ldf(const void* p, int i, bool f32) {
    return f32 ? ((const float*)p)[i] : us2f(((const u16*)p)[i]);
}
__device__ __forceinline__ float wredmax(float v) {
#pragma unroll
    for (int off = 32; off; off >>= 1) v = fmaxf(v, __shfl_xor(v, off));
    return v;
}
__device__ __forceinline__ float wredsum(float v) {
#pragma unroll
    for (int off = 32; off; off >>= 1) v += __shfl_xor(v, off);
    return v;
}

// ---------------- dtype sniff: fp32 data viewed as bf16 has exp==0xFF hits ----------------
__global__ __launch_bounds__(1024) void k_sniff(const u16* __restrict__ x, int* __restrict__ flags) {
    __shared__ int cnt;
    if (threadIdx.x == 0) cnt = 0;
    __syncthreads();
    int c = 0;
#pragma unroll
    for (int it = 0; it < 8; it++) {
        ushort4 a = ((const ushort4*)x)[(it * 1024 + threadIdx.x) * 2];
        ushort4 b = ((const ushort4*)x)[(it * 1024 + threadIdx.x) * 2 + 1];
        c += (((a.x >> 7) & 0xFF) == 0xFF) + (((a.y >> 7) & 0xFF) == 0xFF)
           + (((a.z >> 7) & 0xFF) == 0xFF) + (((a.w >> 7) & 0xFF) == 0xFF)
           + (((b.x >> 7) & 0xFF) == 0xFF) + (((b.y >> 7) & 0xFF) == 0xFF)
           + (((b.z >> 7) & 0xFF) == 0xFF) + (((b.w >> 7) & 0xFF) == 0xFF);
    }
    c += __shfl_xor(c, 32); c += __shfl_xor(c, 16); c += __shfl_xor(c, 8);
    c += __shfl_xor(c, 4);  c += __shfl_xor(c, 2);  c += __shfl_xor(c, 1);
    if ((threadIdx.x & 63) == 0) atomicAdd(&cnt, c);
    __syncthreads();
    if (threadIdx.x == 0) { flags[0] = (cnt > 16) ? 1 : 0; flags[1] = 1; }
}

// ---------------- CSR build ----------------
__global__ void k_zero(int* __restrict__ p, int n) {
    int i = blockIdx.x * 256 + threadIdx.x;
    if (i < n) p[i] = 0;
}
__global__ void k_hist(const int* __restrict__ ei, int* __restrict__ deg) {
    int e = blockIdx.x * 256 + threadIdx.x;
    if (e < EE) atomicAdd(&deg[ei[EE + e]], 1);
}
// 3-phase parallel scan
__global__ __launch_bounds__(256) void k_scan1(const int* __restrict__ deg,
                                               int* __restrict__ bsum) {
    int i = blockIdx.x * 256 + threadIdx.x;
    int v = (i < NN) ? deg[i] : 0;
    __shared__ int red[4];
    int lane = threadIdx.x & 63, w = threadIdx.x >> 6;
#pragma unroll
    for (int off = 32; off; off >>= 1) v += __shfl_xor(v, off);
    if (lane == 0) red[w] = v;
    __syncthreads();
    if (threadIdx.x == 0) bsum[blockIdx.x] = red[0] + red[1] + red[2] + red[3];
}
__global__ __launch_bounds__(256) void k_scan2(const int* __restrict__ bsum,
                                               int* __restrict__ boff,
                                               int* __restrict__ rowptr) {
    __shared__ int s[256];
    int t = threadIdx.x;
    s[t] = (t < 196) ? bsum[t] : 0;
    __syncthreads();
    for (int off = 1; off < 256; off <<= 1) {
        int u = (t >= off) ? s[t - off] : 0;
        __syncthreads();
        s[t] += u;
        __syncthreads();
    }
    if (t < 196) boff[t] = (t == 0) ? 0 : s[t - 1];
    if (t == 255) rowptr[NN] = s[255];
}
__global__ __launch_bounds__(256) void k_scan3(int* __restrict__ deg /*in deg, out cursor*/,
                                               const int* __restrict__ boff,
                                               int* __restrict__ rowptr) {
    __shared__ int s[256];
    int t = threadIdx.x;
    int i = blockIdx.x * 256 + t;
    int v = (i < NN) ? deg[i] : 0;
    s[t] = v;
    __syncthreads();
    for (int off = 1; off < 256; off <<= 1) {
        int u = (t >= off) ? s[t - off] : 0;
        __syncthreads();
        s[t] += u;
        __syncthreads();
    }
    if (i < NN) {
        int val = boff[blockIdx.x] + s[t] - v;  // exclusive
        rowptr[i] = val;
        deg[i] = val;  // cursor copy
    }
}
__global__ void k_scatter(const int* __restrict__ ei, int* __restrict__ cursor,
                          int* __restrict__ elist) {
    int e = blockIdx.x * 256 + threadIdx.x;
    if (e >= EE) return;
    int pos = atomicAdd(&cursor[ei[EE + e]], 1);
    elist[pos] = e;
}

// ---------------- qkw[mat][i][h8] = sum_o W[r][i][o] * (q|k)[o][h] ----------------
__global__ void k_qkw(const void* __restrict__ w1, const void* __restrict__ w2,
                      const void* __restrict__ q1, const void* __restrict__ k1,
                      const void* __restrict__ q2, const void* __restrict__ k2,
                      float* __restrict__ qkw, const int* __restrict__ fl) {
    int idx = blockIdx.x * 256 + threadIdx.x;  // 16*128*8 = 16384
    if (idx >= 16384) return;
    const bool f = fl[0] != 0;
    int mat = idx >> 10;
    int i   = (idx >> 3) & 127;
    int h8  = idx & 7;
    const void* W = (mat >= 8) ? w2 : w1;
    const void* qk = (mat >= 8) ? ((h8 < 4) ? q2 : k2) : ((h8 < 4) ? q1 : k1);
    int h = h8 & 3;
    int r = mat & 7;
    float acc = 0.f;
    for (int o = 0; o < HIDC; o++)
        acc += ldf(W, (r * HIDC + i) * HIDC + o, f) * ldf(qk, o * NHEADS + h, f);
    qkw[idx] = acc;
}

// ---------------- W (+qkw cols) -> MFMA B-fragment order: 9 col-tiles ----------------
__global__ void k_wswz(const void* __restrict__ w1, const void* __restrict__ w2,
                       const float* __restrict__ qkw,
                       u16* __restrict__ Wf2, const int* __restrict__ fl) {
    int idx = blockIdx.x * 256 + threadIdx.x;  // 16 * 2304 = 36864
    if (idx >= 36864) return;
    const bool f = fl[0] != 0;
    int mat = idx / 2304, rest = idx % 2304;
    int c = rest >> 8, q = (rest >> 6) & 3, ln = rest & 63;
    int k0 = q * 32 + (ln >> 4) * 8;
    int nn = c * 16 + (ln & 15);
    int r = mat & 7;
    u16 o[8];
    if (c < 8) {
        const void* W = (mat >= 8) ? w2 : w1;
#pragma unroll
        for (int j = 0; j < 8; j++)
            o[j] = f2us(ldf(W, (r * HIDC + k0 + j) * HIDC + nn, f));
    } else {
        int col = nn - 128;  // 0..15
#pragma unroll
        for (int j = 0; j < 8; j++)
            o[j] = (col < 8) ? f2us(qkw[mat * 1024 + (k0 + j) * 8 + col]) : (u16)0;
    }
    u16* dst = Wf2 + (size_t)mat * 18432 + (size_t)(((c * 4 + q) * 64 + ln) * 8);
    *(ushort4*)dst       = ushort4{o[0], o[1], o[2], o[3]};
    *(ushort4*)(dst + 4) = ushort4{o[4], o[5], o[6], o[7]};
}

// ---------------- MFMA xw + s/t from col-tile 8 ----------------
__global__ __launch_bounds__(256) void k_xw2(const void* __restrict__ X,
                                             const u16* __restrict__ Wf2,
                                             bf16* __restrict__ xw,
                                             float* __restrict__ sbuf,
                                             float* __restrict__ tbuf,
                                             const int* __restrict__ fx,
                                             int layer) {
    __shared__ u16 Xs[64 * 136];    // 17.4 KB bf16 input tile
    __shared__ float Os[64 * 132];  // 33.8 KB fp32 output tile
    const int tid = threadIdx.x;
    const int r = blockIdx.y;
    const int n0 = blockIdx.x * 64;
    const bool xf = fx[0] != 0;
    for (int v = tid; v < 2048; v += 256) {
        int row = v >> 5, c4 = (v & 31) * 4, n = n0 + row;
        ushort4 o = {0, 0, 0, 0};
        if (n < NN) {
            if (xf) {
                float4 hv = *(const float4*)((const float*)X + (size_t)n * HIDC + c4);
                o = ushort4{f2us(hv.x), f2us(hv.y), f2us(hv.z), f2us(hv.w)};
            } else {
                o = *(const ushort4*)((const u16*)X + (size_t)n * HIDC + c4);
            }
        }
        *(ushort4*)&Xs[row * 136 + c4] = o;
    }
    __syncthreads();
    const int w = tid >> 6, lane = tid & 63;
    short8 af[4];
#pragma unroll
    for (int q = 0; q < 4; q++)
        af[q] = *(const short8*)&Xs[(16 * w + (lane & 15)) * 136 + q * 32 + (lane >> 4) * 8];
    const u16* Wfr = Wf2 + (size_t)(layer * 8 + r) * 18432;
#pragma unroll
    for (int c = 0; c < 9; c++) {
        floatx4 acc = {0.f, 0.f, 0.f, 0.f};
#pragma unroll
        for (int q = 0; q < 4; q++) {
            short8 bfr = *(const short8*)&Wfr[(size_t)(((c * 4 + q) * 64 + lane) * 8)];
            acc = __builtin_amdgcn_mfma_f32_16x16x32_bf16(af[q], bfr, acc, 0, 0, 0);
        }
        if (c < 8) {
            int col = c * 16 + (lane & 15);
#pragma unroll
            for (int reg = 0; reg < 4; reg++) {
                int p = 16 * w + (lane >> 4) * 4 + reg;
                Os[p * 132 + col] = acc[reg];
            }
        } else {
            int cl = lane & 15;  // 0..3 -> s heads, 4..7 -> t heads
            if (cl < 8) {
                float* dstp = (cl < 4) ? sbuf : tbuf;
                int h = cl & 3;
#pragma unroll
                for (int reg = 0; reg < 4; reg++) {
                    int p = 16 * w + (lane >> 4) * 4 + reg;
                    int n = n0 + p;
                    if (n < NN) dstp[(size_t)(n * RR + r) * 4 + h] = acc[reg];
                }
            }
        }
    }
    __syncthreads();
    for (int v = tid; v < 2048; v += 256) {
        int row = v >> 5, c4 = (v & 31) * 4, n = n0 + row;
        if (n < NN) {
            float4 hv = *(const float4*)&Os[row * 132 + c4];
            ushort4 o = {f2us(hv.x), f2us(hv.y), f2us(hv.z), f2us(hv.w)};
            *(ushort4*)((u16*)xw + (size_t)(n * RR + r) * HIDC + c4) = o;
        }
    }
}

// ---------------- fused attention: 2 edges in flight via wave halves, shuffle-fed ----------------
// lane = (half, sl): half=lane>>5, sl=lane&31 covers channels sl*4..sl*4+3; head hh=sl>>3
__global__ __launch_bounds__(256) void k_attn(const int* __restrict__ rowptr,
                                              const int* __restrict__ elist,
                                              const int* __restrict__ ei,
                                              const int* __restrict__ et,
                                              const float* __restrict__ sb,
                                              const float* __restrict__ tb,
                                              const bf16* __restrict__ xw,
                                              const void* __restrict__ b,
                                              const void* __restrict__ g,
                                              const void* __restrict__ bb,
                                              const float* __restrict__ hprev,
                                              float* __restrict__ hout,
                                              const int* __restrict__ fl) {
    const int lane = threadIdx.x & 63;
    const int d = blockIdx.x * 4 + (threadIdx.x >> 6);
    if (d >= NN) return;
    const bool f = fl[0] != 0;
    const int half = lane >> 5;
    const int sl = lane & 31;
    const int hh = sl >> 3;
    const int start = rowptr[d], end = rowptr[d + 1];
    float m0 = -1e30f, m1 = -1e30f, m2 = -1e30f, m3 = -1e30f;
    float l0 = 0.f, l1 = 0.f, l2 = 0.f, l3 = 0.f;
    float acc0 = 0.f, acc1 = 0.f, acc2 = 0.f, acc3 = 0.f;
    for (int c0 = start; c0 < end; c0 += 64) {
        int n = end - c0;
        if (n > 64) n = 64;
        float a0, a1, a2, a3;
        int sr = 0;
        if (lane < n) {
            int e = elist[c0 + lane];
            int src = ei[e], r = et[e];
            sr = src * RR + r;
            float4 si = *(const float4*)&sb[(size_t)(d * RR + r) * 4];
            float4 tj = *(const float4*)&tb[(size_t)sr * 4];
            a0 = si.x + tj.x; a0 = a0 >= 0.f ? a0 : 0.2f * a0;
            a1 = si.y + tj.y; a1 = a1 >= 0.f ? a1 : 0.2f * a1;
            a2 = si.z + tj.z; a2 = a2 >= 0.f ? a2 : 0.2f * a2;
            a3 = si.w + tj.w; a3 = a3 >= 0.f ? a3 : 0.2f * a3;
        } else { a0 = a1 = a2 = a3 = -1e30f; }
        float n0 = fmaxf(m0, wredmax(a0));
        float n1 = fmaxf(m1, wredmax(a1));
        float n2 = fmaxf(m2, wredmax(a2));
        float n3 = fmaxf(m3, wredmax(a3));
        float s0 = __expf(m0 - n0), s1 = __expf(m1 - n1);
        float s2 = __expf(m2 - n2), s3 = __expf(m3 - n3);
        float e0 = __expf(a0 - n0), e1 = __expf(a1 - n1);
        float e2 = __expf(a2 - n2), e3 = __expf(a3 - n3);
        l0 = l0 * s0 + wredsum(e0);
        l1 = l1 * s1 + wredsum(e1);
        l2 = l2 * s2 + wredsum(e2);
        l3 = l3 * s3 + wredsum(e3);
        float scl = hh == 0 ? s0 : hh == 1 ? s1 : hh == 2 ? s2 : s3;
        acc0 *= scl; acc1 *= scl; acc2 *= scl; acc3 *= scl;
        // 2 edges in flight: half 0 takes even j, half 1 odd j; e[j>=n]=0 so no tail guard
        for (int j2 = 0; j2 < n; j2 += 2) {
            int jl = j2 + half;
            int srj = __shfl(sr, jl);
            float wx = __shfl(e0, jl), wy = __shfl(e1, jl);
            float wz = __shfl(e2, jl), ww = __shfl(e3, jl);
            float wgt = hh == 0 ? wx : hh == 1 ? wy : hh == 2 ? wz : ww;
            ushort4 u = *(const ushort4*)((const u16*)xw + (size_t)srj * HIDC + sl * 4);
            acc0 += wgt * us2f(u.x);
            acc1 += wgt * us2f(u.y);
            acc2 += wgt * us2f(u.z);
            acc3 += wgt * us2f(u.w);
        }
        m0 = n0; m1 = n1; m2 = n2; m3 = n3;
    }
    // combine the two halves
    acc0 += __shfl_xor(acc0, 32);
    acc1 += __shfl_xor(acc1, 32);
    acc2 += __shfl_xor(acc2, 32);
    acc3 += __shfl_xor(acc3, 32);
    float ld = hh == 0 ? l0 : hh == 1 ? l1 : hh == 2 ? l2 : l3;
    float inv = 1.f / (ld + 1e-16f);
    float v0 = fmaxf(acc0 * inv + ldf(b, sl * 4 + 0, f), 0.f);
    float v1 = fmaxf(acc1 * inv + ldf(b, sl * 4 + 1, f), 0.f);
    float v2 = fmaxf(acc2 * inv + ldf(b, sl * 4 + 2, f), 0.f);
    float v3 = fmaxf(acc3 * inv + ldf(b, sl * 4 + 3, f), 0.f);
    float sum = v0 + v1 + v2 + v3;
#pragma unroll
    for (int off = 16; off; off >>= 1) sum += __shfl_xor(sum, off);
    float mean = sum * (1.f / 128.f);
    v0 -= mean; v1 -= mean; v2 -= mean; v3 -= mean;
    float sq = v0 * v0 + v1 * v1 + v2 * v2 + v3 * v3;
#pragma unroll
    for (int off = 16; off; off >>= 1) sq += __shfl_xor(sq, off);
    float rstd = rsqrtf(sq * (1.f / 128.f) + 1e-5f);
    if (half == 0) {
        float y0 = v0 * rstd * ldf(g, sl * 4 + 0, f) + ldf(bb, sl * 4 + 0, f);
        float y1 = v1 * rstd * ldf(g, sl * 4 + 1, f) + ldf(bb, sl * 4 + 1, f);
        float y2 = v2 * rstd * ldf(g, sl * 4 + 2, f) + ldf(bb, sl * 4 + 2, f);
        float y3 = v3 * rstd * ldf(g, sl * 4 + 3, f) + ldf(bb, sl * 4 + 3, f);
        if (hprev) {
            float4 hv = *(const float4*)&hprev[(size_t)d * HIDC + sl * 4];
            y0 += hv.x; y1 += hv.y; y2 += hv.z; y3 += hv.w;
        }
        *(float4*)&hout[(size_t)d * HIDC + sl * 4] = float4{y0, y1, y2, y3};
    }
}

// ---------------- mw1 + mw2 -> B-fragment order (bf16) for MFMA decode ----------------
__global__ void k_dswz(const void* __restrict__ mw1, const void* __restrict__ mw2,
                       u16* __restrict__ Wf, const int* __restrict__ fl) {
    int idx = blockIdx.x * 256 + threadIdx.x;  // 0..4351
    if (idx >= 4352) return;
    const bool f = fl[0] != 0;
    u16 o[8];
    if (idx < 4096) {
        int c = idx >> 9, q = (idx >> 6) & 7, ln = idx & 63;
        int k0 = q * 32 + (ln >> 4) * 8;
        int nn = c * 16 + (ln & 15);
#pragma unroll
        for (int j = 0; j < 8; j++)
            o[j] = f2us(ldf(mw1, (k0 + j) * HIDC + nn, f));
    } else {
        int fidx = idx - 4096;           // q*64 + lane
        int q = fidx >> 6, ln = fidx & 63;
        int k0 = q * 32 + (ln >> 4) * 8;
        int nn = ln & 15;
#pragma unroll
        for (int j = 0; j < 8; j++)
            o[j] = (nn < 8) ? f2us(ldf(mw2, (k0 + j) * NCL + nn, f)) : (u16)0;
    }
    *(ushort4*)&Wf[idx * 8]     = ushort4{o[0], o[1], o[2], o[3]};
    *(ushort4*)&Wf[idx * 8 + 4] = ushort4{o[4], o[5], o[6], o[7]};
}

// ---------------- decode: barrier-free, direct global A-fragment gathers ----------------
__global__ __launch_bounds__(256) void k_decode2(const float* __restrict__ h,
                                                 const int* __restrict__ edges,
                                                 const u16* __restrict__ Wf,
                                                 const void* __restrict__ mb1,
                                                 const void* __restrict__ mb2,
                                                 void* __restrict__ out,
                                                 const int* __restrict__ fl) {
    __shared__ u16 zsu[64 * 136];   // 17.4 KB, wave-local rows only
    const int tid = threadIdx.x;
    const bool f = fl[0] != 0;
    const int p0 = blockIdx.x * 64;
    const int w = tid >> 6, lane = tid & 63;
    const int m = 16 * w + (lane & 15);   // row in 64-tile
    const int g = lane >> 4;              // k-group 0..3
    const int na = edges[(size_t)(p0 + m) * 2];
    const int nb = edges[(size_t)(p0 + m) * 2 + 1];
    short8 af[8];
#pragma unroll
    for (int q = 0; q < 8; q++) {
        int k0 = q * 32 + g * 8;          // 0..248
        const float* src = h + (size_t)((k0 >> 7) ? nb : na) * HIDC + (k0 & 127);
        float4 a = *(const float4*)src;
        float4 bq = *(const float4*)(src + 4);
        u16 tmp[8] = {f2us(a.x), f2us(a.y), f2us(a.z), f2us(a.w),
                      f2us(bq.x), f2us(bq.y), f2us(bq.z), f2us(bq.w)};
        af[q] = *(short8*)tmp;
    }
#pragma unroll
    for (int c = 0; c < 8; c++) {
        floatx4 acc = {0.f, 0.f, 0.f, 0.f};
#pragma unroll
        for (int q = 0; q < 8; q++) {
            short8 bfr = *(const short8*)&Wf[(size_t)(((c * 8 + q) * 64 + lane) * 8)];
            acc = __builtin_amdgcn_mfma_f32_16x16x32_bf16(af[q], bfr, acc, 0, 0, 0);
        }
        int col = c * 16 + (lane & 15);
        float bv = ldf(mb1, col, f);
#pragma unroll
        for (int reg = 0; reg < 4; reg++) {
            int p = 16 * w + (lane >> 4) * 4 + reg;
            float z = acc[reg] + bv;
            zsu[p * 136 + col] = f2us(0.5f * z * (1.f + erff(z * 0.70710678118654752f)));
        }
    }
    // second GEMM: rows wave-local -> no barrier
    floatx4 acc2 = {0.f, 0.f, 0.f, 0.f};
#pragma unroll
    for (int q = 0; q < 4; q++) {
        short8 af2 = *(const short8*)&zsu[m * 136 + q * 32 + g * 8];
        short8 bfr2 = *(const short8*)&Wf[32768 + (size_t)((q * 64 + lane) * 8)];
        acc2 = __builtin_amdgcn_mfma_f32_16x16x32_bf16(af2, bfr2, acc2, 0, 0, 0);
    }
    int col16 = lane & 15;
    if (col16 < 8) {
        float bv2 = ldf(mb2, col16, f);
#pragma unroll
        for (int reg = 0; reg < 4; reg++) {
            int p = 16 * w + (lane >> 4) * 4 + reg;
            float sv = acc2[reg] + bv2;
            size_t oi = (size_t)(p0 + p) * NCL + col16;
            if (f) ((float*)out)[oi] = sv;
            else   ((bf16*)out)[oi] = __float2bfloat16(sv);
        }
    }
}

extern "C" void kernel_launch(void* const* d_in, const int* in_sizes, int n_in,
                              void* d_out, int out_size, void* d_ws, size_t ws_size,
                              hipStream_t stream) {
    (void)in_sizes; (void)n_in; (void)out_size; (void)ws_size;
    const void* x    = d_in[0];
    const int* ei    = (const int*)d_in[1];
    const int* et    = (const int*)d_in[2];
    const int* edges = (const int*)d_in[3];
    const void* w1 = d_in[4];
    const void* q1 = d_in[5];
    const void* k1 = d_in[6];
    const void* b1 = d_in[7];
    const void* w2 = d_in[8];
    const void* q2 = d_in[9];
    const void* k2 = d_in[10];
    const void* b2 = d_in[11];
    const void* ln1g = d_in[12];
    const void* ln1b = d_in[13];
    const void* ln2g = d_in[14];
    const void* ln2b = d_in[15];
    const void* mw1 = d_in[16];
    const void* mb1 = d_in[17];
    const void* mw2 = d_in[18];
    const void* mb2 = d_in[19];

    // workspace layout — within round-3-proven bound (<= 169,425,560 B)
    char* ws = (char*)d_ws;
    bf16* xwb   = (bf16*)ws;                      // [0, 102,400,000)
    u16* Wf     = (u16*)ws;                       // ALIAS xwb: k_dswz runs after last xwb read (69,632 B)
    float* sbuf = (float*)(ws + 102400000);       // 6.4 MB
    float* tbuf = (float*)(ws + 108800000);       // 6.4 MB
    float* h1   = (float*)(ws + 115200000);       // 25.6 MB
    float* hsum = (float*)(ws + 140800000);       // 25.6 MB
    u16* Wf2    = (u16*)(ws + 140800000);         // ALIAS hsum: dead before hsum is written (589,824 B)
    int* rowptr = (int*)(ws + 166400000);         // NN+1 ints
    int* cursor = (int*)(ws + 166600016);         // NN ints
    int* elist  = (int*)(ws + 166800016);         // EE ints
    float* qkw  = (float*)(ws + 169360016);       // 65,536 B -> ends 169,425,552
    int* bsum   = (int*)qkw;                      // ALIAS qkw: scan phases finish before k_qkw writes
    int* boff   = bsum + 256;
    int* flags  = (int*)(ws + 169425552);         // 8 B -> ends 169,425,560 (proven)

    k_sniff<<<1, 1024, 0, stream>>>((const u16*)x, flags);

    // CSR build (parallel 3-phase scan) + weight preprocessing
    k_zero<<<196, 256, 0, stream>>>(cursor, NN);
    k_hist<<<2500, 256, 0, stream>>>(ei, cursor);
    k_scan1<<<196, 256, 0, stream>>>(cursor, bsum);
    k_scan2<<<1, 256, 0, stream>>>(bsum, boff, rowptr);
    k_scan3<<<196, 256, 0, stream>>>(cursor, boff, rowptr);
    k_scatter<<<2500, 256, 0, stream>>>(ei, cursor, elist);
    k_qkw<<<64, 256, 0, stream>>>(w1, w2, q1, k1, q2, k2, qkw, flags);
    k_wswz<<<144, 256, 0, stream>>>(w1, w2, qkw, Wf2, flags);

    for (int layer = 0; layer < 2; ++layer) {
        const void* b  = layer ? b2 : b1;
        const void* lg = layer ? ln2g : ln1g;
        const void* lb = layer ? ln2b : ln1b;
        k_xw2<<<dim3(782, 8), 256, 0, stream>>>(layer ? (const void*)h1 : x, Wf2, xwb,
                                                sbuf, tbuf,
                                                layer ? flags + 1 : flags, layer);
        k_attn<<<12500, 256, 0, stream>>>(rowptr, elist, ei, et, sbuf, tbuf, xwb,
                                          b, lg, lb,
                                          layer ? h1 : (const float*)nullptr,
                                          layer ? hsum : h1, flags);
    }
    // decode weight swizzle into xwb space (xwb dead after attn L1)
    k_dswz<<<17, 256, 0, stream>>>(mw1, mw2, Wf, flags);
    k_decode2<<<3125, 256, 0, stream>>>(hsum, edges, Wf, mb1, mb2, d_out, flags);
}

// Round 14
// 505.106 us; speedup vs baseline: 1.1800x; 1.0561x over previous
//
#include <hip/hip_runtime.h>
#include <hip/hip_bf16.h>

#define NN    50000
#define RR    8
#define HIDC  128
#define NHEADS 4
#define EE    640000
#define EE2   200000
#define NCL   8

typedef __hip_bfloat16 bf16;
typedef unsigned short u16;
typedef __attribute__((ext_vector_type(8))) short short8;
typedef __attribute__((ext_vector_type(4))) float floatx4;

__device__ __forceinline__ float us2f(u16 u) {
    return __uint_as_float(((unsigned)u) << 16);
}
__device__ __forceinline__ float bf2f(bf16 v) { return __bfloat162float(v); }
__device__ __forceinline__ u16 f2us(float f) {
    bf16 h = __float2bfloat16(f);
    return *(u16*)&h;
}
__device__ __forceinline__ float ldf(const void* p, int i, bool f32) {
    return f32 ? ((const float*)p)[i] : us2f(((const u16*)p)[i]);
}
__device__ __forceinline__ float wredmax(float v) {
#pragma unroll
    for (int off = 32; off; off >>= 1) v = fmaxf(v, __shfl_xor(v, off));
    return v;
}
__device__ __forceinline__ float wredsum(float v) {
#pragma unroll
    for (int off = 32; off; off >>= 1) v += __shfl_xor(v, off);
    return v;
}

// ---------------- dtype sniff: fp32 data viewed as bf16 has exp==0xFF hits ----------------
__global__ __launch_bounds__(1024) void k_sniff(const u16* __restrict__ x, int* __restrict__ flags) {
    __shared__ int cnt;
    if (threadIdx.x == 0) cnt = 0;
    __syncthreads();
    int c = 0;
#pragma unroll
    for (int it = 0; it < 8; it++) {
        ushort4 a = ((const ushort4*)x)[(it * 1024 + threadIdx.x) * 2];
        ushort4 b = ((const ushort4*)x)[(it * 1024 + threadIdx.x) * 2 + 1];
        c += (((a.x >> 7) & 0xFF) == 0xFF) + (((a.y >> 7) & 0xFF) == 0xFF)
           + (((a.z >> 7) & 0xFF) == 0xFF) + (((a.w >> 7) & 0xFF) == 0xFF)
           + (((b.x >> 7) & 0xFF) == 0xFF) + (((b.y >> 7) & 0xFF) == 0xFF)
           + (((b.z >> 7) & 0xFF) == 0xFF) + (((b.w >> 7) & 0xFF) == 0xFF);
    }
    c += __shfl_xor(c, 32); c += __shfl_xor(c, 16); c += __shfl_xor(c, 8);
    c += __shfl_xor(c, 4);  c += __shfl_xor(c, 2);  c += __shfl_xor(c, 1);
    if ((threadIdx.x & 63) == 0) atomicAdd(&cnt, c);
    __syncthreads();
    if (threadIdx.x == 0) { flags[0] = (cnt > 16) ? 1 : 0; flags[1] = 0; }  // [1]=0: internal bf16
}

// ---------------- CSR build ----------------
__global__ void k_zero(int* __restrict__ p, int n) {
    int i = blockIdx.x * 256 + threadIdx.x;
    if (i < n) p[i] = 0;
}
__global__ void k_hist(const int* __restrict__ ei, int* __restrict__ deg) {
    int e = blockIdx.x * 256 + threadIdx.x;
    if (e < EE) atomicAdd(&deg[ei[EE + e]], 1);
}
// 3-phase parallel scan
__global__ __launch_bounds__(256) void k_scan1(const int* __restrict__ deg,
                                               int* __restrict__ bsum) {
    int i = blockIdx.x * 256 + threadIdx.x;
    int v = (i < NN) ? deg[i] : 0;
    __shared__ int red[4];
    int lane = threadIdx.x & 63, w = threadIdx.x >> 6;
#pragma unroll
    for (int off = 32; off; off >>= 1) v += __shfl_xor(v, off);
    if (lane == 0) red[w] = v;
    __syncthreads();
    if (threadIdx.x == 0) bsum[blockIdx.x] = red[0] + red[1] + red[2] + red[3];
}
__global__ __launch_bounds__(256) void k_scan2(const int* __restrict__ bsum,
                                               int* __restrict__ boff,
                                               int* __restrict__ rowptr) {
    __shared__ int s[256];
    int t = threadIdx.x;
    s[t] = (t < 196) ? bsum[t] : 0;
    __syncthreads();
    for (int off = 1; off < 256; off <<= 1) {
        int u = (t >= off) ? s[t - off] : 0;
        __syncthreads();
        s[t] += u;
        __syncthreads();
    }
    if (t < 196) boff[t] = (t == 0) ? 0 : s[t - 1];
    if (t == 255) rowptr[NN] = s[255];
}
__global__ __launch_bounds__(256) void k_scan3(int* __restrict__ deg /*in deg, out cursor*/,
                                               const int* __restrict__ boff,
                                               int* __restrict__ rowptr) {
    __shared__ int s[256];
    int t = threadIdx.x;
    int i = blockIdx.x * 256 + t;
    int v = (i < NN) ? deg[i] : 0;
    s[t] = v;
    __syncthreads();
    for (int off = 1; off < 256; off <<= 1) {
        int u = (t >= off) ? s[t - off] : 0;
        __syncthreads();
        s[t] += u;
        __syncthreads();
    }
    if (i < NN) {
        int val = boff[blockIdx.x] + s[t] - v;  // exclusive
        rowptr[i] = val;
        deg[i] = val;  // cursor copy
    }
}
__global__ void k_scatter(const int* __restrict__ ei, int* __restrict__ cursor,
                          int* __restrict__ elist) {
    int e = blockIdx.x * 256 + threadIdx.x;
    if (e >= EE) return;
    int pos = atomicAdd(&cursor[ei[EE + e]], 1);
    elist[pos] = e;
}

// ---------------- qkw[mat][i][h8] = sum_o W[r][i][o] * (q|k)[o][h] ----------------
__global__ void k_qkw(const void* __restrict__ w1, const void* __restrict__ w2,
                      const void* __restrict__ q1, const void* __restrict__ k1,
                      const void* __restrict__ q2, const void* __restrict__ k2,
                      float* __restrict__ qkw, const int* __restrict__ fl) {
    int idx = blockIdx.x * 256 + threadIdx.x;  // 16*128*8 = 16384
    if (idx >= 16384) return;
    const bool f = fl[0] != 0;
    int mat = idx >> 10;
    int i   = (idx >> 3) & 127;
    int h8  = idx & 7;
    const void* W = (mat >= 8) ? w2 : w1;
    const void* qk = (mat >= 8) ? ((h8 < 4) ? q2 : k2) : ((h8 < 4) ? q1 : k1);
    int h = h8 & 3;
    int r = mat & 7;
    float acc = 0.f;
    for (int o = 0; o < HIDC; o++)
        acc += ldf(W, (r * HIDC + i) * HIDC + o, f) * ldf(qk, o * NHEADS + h, f);
    qkw[idx] = acc;
}

// ---------------- W (+qkw cols) -> MFMA B-fragment order: 9 col-tiles ----------------
__global__ void k_wswz(const void* __restrict__ w1, const void* __restrict__ w2,
                       const float* __restrict__ qkw,
                       u16* __restrict__ Wf2, const int* __restrict__ fl) {
    int idx = blockIdx.x * 256 + threadIdx.x;  // 16 * 2304 = 36864
    if (idx >= 36864) return;
    const bool f = fl[0] != 0;
    int mat = idx / 2304, rest = idx % 2304;
    int c = rest >> 8, q = (rest >> 6) & 3, ln = rest & 63;
    int k0 = q * 32 + (ln >> 4) * 8;
    int nn = c * 16 + (ln & 15);
    int r = mat & 7;
    u16 o[8];
    if (c < 8) {
        const void* W = (mat >= 8) ? w2 : w1;
#pragma unroll
        for (int j = 0; j < 8; j++)
            o[j] = f2us(ldf(W, (r * HIDC + k0 + j) * HIDC + nn, f));
    } else {
        int col = nn - 128;  // 0..15
#pragma unroll
        for (int j = 0; j < 8; j++)
            o[j] = (col < 8) ? f2us(qkw[mat * 1024 + (k0 + j) * 8 + col]) : (u16)0;
    }
    u16* dst = Wf2 + (size_t)mat * 18432 + (size_t)(((c * 4 + q) * 64 + ln) * 8);
    *(ushort4*)dst       = ushort4{o[0], o[1], o[2], o[3]};
    *(ushort4*)(dst + 4) = ushort4{o[4], o[5], o[6], o[7]};
}

// ---------------- MFMA xw + s/t from col-tile 8 ----------------
__global__ __launch_bounds__(256) void k_xw2(const void* __restrict__ X,
                                             const u16* __restrict__ Wf2,
                                             bf16* __restrict__ xw,
                                             float* __restrict__ sbuf,
                                             float* __restrict__ tbuf,
                                             const int* __restrict__ fx,
                                             int layer) {
    __shared__ u16 Xs[64 * 136];    // 17.4 KB bf16 input tile
    __shared__ float Os[64 * 132];  // 33.8 KB fp32 output tile
    const int tid = threadIdx.x;
    const int r = blockIdx.y;
    const int n0 = blockIdx.x * 64;
    const bool xf = fx[0] != 0;
    for (int v = tid; v < 2048; v += 256) {
        int row = v >> 5, c4 = (v & 31) * 4, n = n0 + row;
        ushort4 o = {0, 0, 0, 0};
        if (n < NN) {
            if (xf) {
                float4 hv = *(const float4*)((const float*)X + (size_t)n * HIDC + c4);
                o = ushort4{f2us(hv.x), f2us(hv.y), f2us(hv.z), f2us(hv.w)};
            } else {
                o = *(const ushort4*)((const u16*)X + (size_t)n * HIDC + c4);
            }
        }
        *(ushort4*)&Xs[row * 136 + c4] = o;
    }
    __syncthreads();
    const int w = tid >> 6, lane = tid & 63;
    short8 af[4];
#pragma unroll
    for (int q = 0; q < 4; q++)
        af[q] = *(const short8*)&Xs[(16 * w + (lane & 15)) * 136 + q * 32 + (lane >> 4) * 8];
    const u16* Wfr = Wf2 + (size_t)(layer * 8 + r) * 18432;
#pragma unroll
    for (int c = 0; c < 9; c++) {
        floatx4 acc = {0.f, 0.f, 0.f, 0.f};
#pragma unroll
        for (int q = 0; q < 4; q++) {
            short8 bfr = *(const short8*)&Wfr[(size_t)(((c * 4 + q) * 64 + lane) * 8)];
            acc = __builtin_amdgcn_mfma_f32_16x16x32_bf16(af[q], bfr, acc, 0, 0, 0);
        }
        if (c < 8) {
            int col = c * 16 + (lane & 15);
#pragma unroll
            for (int reg = 0; reg < 4; reg++) {
                int p = 16 * w + (lane >> 4) * 4 + reg;
                Os[p * 132 + col] = acc[reg];
            }
        } else {
            int cl = lane & 15;  // 0..3 -> s heads, 4..7 -> t heads
            if (cl < 8) {
                float* dstp = (cl < 4) ? sbuf : tbuf;
                int h = cl & 3;
#pragma unroll
                for (int reg = 0; reg < 4; reg++) {
                    int p = 16 * w + (lane >> 4) * 4 + reg;
                    int n = n0 + p;
                    if (n < NN) dstp[(size_t)(n * RR + r) * 4 + h] = acc[reg];
                }
            }
        }
    }
    __syncthreads();
    for (int v = tid; v < 2048; v += 256) {
        int row = v >> 5, c4 = (v & 31) * 4, n = n0 + row;
        if (n < NN) {
            float4 hv = *(const float4*)&Os[row * 132 + c4];
            ushort4 o = {f2us(hv.x), f2us(hv.y), f2us(hv.z), f2us(hv.w)};
            *(ushort4*)((u16*)xw + (size_t)(n * RR + r) * HIDC + c4) = o;
        }
    }
}

// ---------------- fused attention: 2 edges in flight via wave halves, shuffle-fed ----------------
// lane = (half, sl): half=lane>>5, sl=lane&31 covers channels sl*4..sl*4+3; head hh=sl>>3
// hprev/hout are internal bf16 [N][128]
__global__ __launch_bounds__(256) void k_attn(const int* __restrict__ rowptr,
                                              const int* __restrict__ elist,
                                              const int* __restrict__ ei,
                                              const int* __restrict__ et,
                                              const float* __restrict__ sb,
                                              const float* __restrict__ tb,
                                              const bf16* __restrict__ xw,
                                              const void* __restrict__ b,
                                              const void* __restrict__ g,
                                              const void* __restrict__ bb,
                                              const u16* __restrict__ hprev,
                                              u16* __restrict__ hout,
                                              const int* __restrict__ fl) {
    const int lane = threadIdx.x & 63;
    const int d = blockIdx.x * 4 + (threadIdx.x >> 6);
    if (d >= NN) return;
    const bool f = fl[0] != 0;
    const int half = lane >> 5;
    const int sl = lane & 31;
    const int hh = sl >> 3;
    const int start = rowptr[d], end = rowptr[d + 1];
    float m0 = -1e30f, m1 = -1e30f, m2 = -1e30f, m3 = -1e30f;
    float l0 = 0.f, l1 = 0.f, l2 = 0.f, l3 = 0.f;
    float acc0 = 0.f, acc1 = 0.f, acc2 = 0.f, acc3 = 0.f;
    for (int c0 = start; c0 < end; c0 += 64) {
        int n = end - c0;
        if (n > 64) n = 64;
        float a0, a1, a2, a3;
        int sr = 0;
        if (lane < n) {
            int e = elist[c0 + lane];
            int src = ei[e], r = et[e];
            sr = src * RR + r;
            float4 si = *(const float4*)&sb[(size_t)(d * RR + r) * 4];
            float4 tj = *(const float4*)&tb[(size_t)sr * 4];
            a0 = si.x + tj.x; a0 = a0 >= 0.f ? a0 : 0.2f * a0;
            a1 = si.y + tj.y; a1 = a1 >= 0.f ? a1 : 0.2f * a1;
            a2 = si.z + tj.z; a2 = a2 >= 0.f ? a2 : 0.2f * a2;
            a3 = si.w + tj.w; a3 = a3 >= 0.f ? a3 : 0.2f * a3;
        } else { a0 = a1 = a2 = a3 = -1e30f; }
        float n0 = fmaxf(m0, wredmax(a0));
        float n1 = fmaxf(m1, wredmax(a1));
        float n2 = fmaxf(m2, wredmax(a2));
        float n3 = fmaxf(m3, wredmax(a3));
        float s0 = __expf(m0 - n0), s1 = __expf(m1 - n1);
        float s2 = __expf(m2 - n2), s3 = __expf(m3 - n3);
        float e0 = __expf(a0 - n0), e1 = __expf(a1 - n1);
        float e2 = __expf(a2 - n2), e3 = __expf(a3 - n3);
        l0 = l0 * s0 + wredsum(e0);
        l1 = l1 * s1 + wredsum(e1);
        l2 = l2 * s2 + wredsum(e2);
        l3 = l3 * s3 + wredsum(e3);
        float scl = hh == 0 ? s0 : hh == 1 ? s1 : hh == 2 ? s2 : s3;
        acc0 *= scl; acc1 *= scl; acc2 *= scl; acc3 *= scl;
        // 2 edges in flight: half 0 takes even j, half 1 odd j; e[j>=n]=0 so no tail guard
        for (int j2 = 0; j2 < n; j2 += 2) {
            int jl = j2 + half;
            int srj = __shfl(sr, jl);
            float wx = __shfl(e0, jl), wy = __shfl(e1, jl);
            float wz = __shfl(e2, jl), ww = __shfl(e3, jl);
            float wgt = hh == 0 ? wx : hh == 1 ? wy : hh == 2 ? wz : ww;
            ushort4 u = *(const ushort4*)((const u16*)xw + (size_t)srj * HIDC + sl * 4);
            acc0 += wgt * us2f(u.x);
            acc1 += wgt * us2f(u.y);
            acc2 += wgt * us2f(u.z);
            acc3 += wgt * us2f(u.w);
        }
        m0 = n0; m1 = n1; m2 = n2; m3 = n3;
    }
    // combine the two halves
    acc0 += __shfl_xor(acc0, 32);
    acc1 += __shfl_xor(acc1, 32);
    acc2 += __shfl_xor(acc2, 32);
    acc3 += __shfl_xor(acc3, 32);
    float ld = hh == 0 ? l0 : hh == 1 ? l1 : hh == 2 ? l2 : l3;
    float inv = 1.f / (ld + 1e-16f);
    float v0 = fmaxf(acc0 * inv + ldf(b, sl * 4 + 0, f), 0.f);
    float v1 = fmaxf(acc1 * inv + ldf(b, sl * 4 + 1, f), 0.f);
    float v2 = fmaxf(acc2 * inv + ldf(b, sl * 4 + 2, f), 0.f);
    float v3 = fmaxf(acc3 * inv + ldf(b, sl * 4 + 3, f), 0.f);
    float sum = v0 + v1 + v2 + v3;
#pragma unroll
    for (int off = 16; off; off >>= 1) sum += __shfl_xor(sum, off);
    float mean = sum * (1.f / 128.f);
    v0 -= mean; v1 -= mean; v2 -= mean; v3 -= mean;
    float sq = v0 * v0 + v1 * v1 + v2 * v2 + v3 * v3;
#pragma unroll
    for (int off = 16; off; off >>= 1) sq += __shfl_xor(sq, off);
    float rstd = rsqrtf(sq * (1.f / 128.f) + 1e-5f);
    if (half == 0) {
        float y0 = v0 * rstd * ldf(g, sl * 4 + 0, f) + ldf(bb, sl * 4 + 0, f);
        float y1 = v1 * rstd * ldf(g, sl * 4 + 1, f) + ldf(bb, sl * 4 + 1, f);
        float y2 = v2 * rstd * ldf(g, sl * 4 + 2, f) + ldf(bb, sl * 4 + 2, f);
        float y3 = v3 * rstd * ldf(g, sl * 4 + 3, f) + ldf(bb, sl * 4 + 3, f);
        if (hprev) {
            ushort4 hv = *(const ushort4*)&hprev[(size_t)d * HIDC + sl * 4];
            y0 += us2f(hv.x); y1 += us2f(hv.y); y2 += us2f(hv.z); y3 += us2f(hv.w);
        }
        ushort4 o = {f2us(y0), f2us(y1), f2us(y2), f2us(y3)};
        *(ushort4*)&hout[(size_t)d * HIDC + sl * 4] = o;
    }
}

// ---------------- mw1 + mw2 -> B-fragment order (bf16) for MFMA decode ----------------
__global__ void k_dswz(const void* __restrict__ mw1, const void* __restrict__ mw2,
                       u16* __restrict__ Wf, const int* __restrict__ fl) {
    int idx = blockIdx.x * 256 + threadIdx.x;  // 0..4351
    if (idx >= 4352) return;
    const bool f = fl[0] != 0;
    u16 o[8];
    if (idx < 4096) {
        int c = idx >> 9, q = (idx >> 6) & 7, ln = idx & 63;
        int k0 = q * 32 + (ln >> 4) * 8;
        int nn = c * 16 + (ln & 15);
#pragma unroll
        for (int j = 0; j < 8; j++)
            o[j] = f2us(ldf(mw1, (k0 + j) * HIDC + nn, f));
    } else {
        int fidx = idx - 4096;           // q*64 + lane
        int q = fidx >> 6, ln = fidx & 63;
        int k0 = q * 32 + (ln >> 4) * 8;
        int nn = ln & 15;
#pragma unroll
        for (int j = 0; j < 8; j++)
            o[j] = (nn < 8) ? f2us(ldf(mw2, (k0 + j) * NCL + nn, f)) : (u16)0;
    }
    *(ushort4*)&Wf[idx * 8]     = ushort4{o[0], o[1], o[2], o[3]};
    *(ushort4*)&Wf[idx * 8 + 4] = ushort4{o[4], o[5], o[6], o[7]};
}

// ---------------- decode: barrier-free, direct bf16 A-fragment gathers ----------------
__global__ __launch_bounds__(256) void k_decode2(const u16* __restrict__ h,
                                                 const int* __restrict__ edges,
                                                 const u16* __restrict__ Wf,
                                                 const void* __restrict__ mb1,
                                                 const void* __restrict__ mb2,
                                                 void* __restrict__ out,
                                                 const int* __restrict__ fl) {
    __shared__ u16 zsu[64 * 136];   // 17.4 KB, wave-local rows only
    const int tid = threadIdx.x;
    const bool f = fl[0] != 0;
    const int p0 = blockIdx.x * 64;
    const int w = tid >> 6, lane = tid & 63;
    const int m = 16 * w + (lane & 15);   // row in 64-tile
    const int g = lane >> 4;              // k-group 0..3
    const int na = edges[(size_t)(p0 + m) * 2];
    const int nb = edges[(size_t)(p0 + m) * 2 + 1];
    short8 af[8];
#pragma unroll
    for (int q = 0; q < 8; q++) {
        int k0 = q * 32 + g * 8;          // 0..248
        af[q] = *(const short8*)(h + (size_t)((k0 >> 7) ? nb : na) * HIDC + (k0 & 127));
    }
#pragma unroll
    for (int c = 0; c < 8; c++) {
        floatx4 acc = {0.f, 0.f, 0.f, 0.f};
#pragma unroll
        for (int q = 0; q < 8; q++) {
            short8 bfr = *(const short8*)&Wf[(size_t)(((c * 8 + q) * 64 + lane) * 8)];
            acc = __builtin_amdgcn_mfma_f32_16x16x32_bf16(af[q], bfr, acc, 0, 0, 0);
        }
        int col = c * 16 + (lane & 15);
        float bv = ldf(mb1, col, f);
#pragma unroll
        for (int reg = 0; reg < 4; reg++) {
            int p = 16 * w + (lane >> 4) * 4 + reg;
            float z = acc[reg] + bv;
            zsu[p * 136 + col] = f2us(0.5f * z * (1.f + erff(z * 0.70710678118654752f)));
        }
    }
    // second GEMM: rows wave-local -> no barrier
    floatx4 acc2 = {0.f, 0.f, 0.f, 0.f};
#pragma unroll
    for (int q = 0; q < 4; q++) {
        short8 af2 = *(const short8*)&zsu[m * 136 + q * 32 + g * 8];
        short8 bfr2 = *(const short8*)&Wf[32768 + (size_t)((q * 64 + lane) * 8)];
        acc2 = __builtin_amdgcn_mfma_f32_16x16x32_bf16(af2, bfr2, acc2, 0, 0, 0);
    }
    int col16 = lane & 15;
    if (col16 < 8) {
        float bv2 = ldf(mb2, col16, f);
#pragma unroll
        for (int reg = 0; reg < 4; reg++) {
            int p = 16 * w + (lane >> 4) * 4 + reg;
            float sv = acc2[reg] + bv2;
            size_t oi = (size_t)(p0 + p) * NCL + col16;
            if (f) ((float*)out)[oi] = sv;
            else   ((bf16*)out)[oi] = __float2bfloat16(sv);
        }
    }
}

extern "C" void kernel_launch(void* const* d_in, const int* in_sizes, int n_in,
                              void* d_out, int out_size, void* d_ws, size_t ws_size,
                              hipStream_t stream) {
    (void)in_sizes; (void)n_in; (void)out_size; (void)ws_size;
    const void* x    = d_in[0];
    const int* ei    = (const int*)d_in[1];
    const int* et    = (const int*)d_in[2];
    const int* edges = (const int*)d_in[3];
    const void* w1 = d_in[4];
    const void* q1 = d_in[5];
    const void* k1 = d_in[6];
    const void* b1 = d_in[7];
    const void* w2 = d_in[8];
    const void* q2 = d_in[9];
    const void* k2 = d_in[10];
    const void* b2 = d_in[11];
    const void* ln1g = d_in[12];
    const void* ln1b = d_in[13];
    const void* ln2g = d_in[14];
    const void* ln2b = d_in[15];
    const void* mw1 = d_in[16];
    const void* mb1 = d_in[17];
    const void* mw2 = d_in[18];
    const void* mb2 = d_in[19];

    // workspace layout — within round-3-proven bound (<= 169,425,560 B)
    char* ws = (char*)d_ws;
    bf16* xwb   = (bf16*)ws;                      // [0, 102,400,000)
    u16* Wf     = (u16*)ws;                       // ALIAS xwb: k_dswz runs after last xwb read (69,632 B)
    float* sbuf = (float*)(ws + 102400000);       // 6.4 MB
    float* tbuf = (float*)(ws + 108800000);       // 6.4 MB
    u16* h1     = (u16*)(ws + 115200000);         // 12.8 MB (bf16 now)
    u16* hsum   = (u16*)(ws + 140800000);         // 12.8 MB (bf16 now)
    u16* Wf2    = (u16*)(ws + 153600000);         // 589,824 B (no longer aliases hsum)
    int* rowptr = (int*)(ws + 166400000);         // NN+1 ints
    int* cursor = (int*)(ws + 166600016);         // NN ints
    int* elist  = (int*)(ws + 166800016);         // EE ints
    float* qkw  = (float*)(ws + 169360016);       // 65,536 B -> ends 169,425,552
    int* bsum   = (int*)qkw;                      // ALIAS qkw: scan phases finish before k_qkw writes
    int* boff   = bsum + 256;
    int* flags  = (int*)(ws + 169425552);         // 8 B -> ends 169,425,560 (proven)

    k_sniff<<<1, 1024, 0, stream>>>((const u16*)x, flags);

    // CSR build (parallel 3-phase scan) + weight preprocessing
    k_zero<<<196, 256, 0, stream>>>(cursor, NN);
    k_hist<<<2500, 256, 0, stream>>>(ei, cursor);
    k_scan1<<<196, 256, 0, stream>>>(cursor, bsum);
    k_scan2<<<1, 256, 0, stream>>>(bsum, boff, rowptr);
    k_scan3<<<196, 256, 0, stream>>>(cursor, boff, rowptr);
    k_scatter<<<2500, 256, 0, stream>>>(ei, cursor, elist);
    k_qkw<<<64, 256, 0, stream>>>(w1, w2, q1, k1, q2, k2, qkw, flags);
    k_wswz<<<144, 256, 0, stream>>>(w1, w2, qkw, Wf2, flags);

    for (int layer = 0; layer < 2; ++layer) {
        const void* b  = layer ? b2 : b1;
        const void* lg = layer ? ln2g : ln1g;
        const void* lb = layer ? ln2b : ln1b;
        // layer-1 input h1 is internal bf16 -> flags+1 (==0); layer-0 input x per sniff
        k_xw2<<<dim3(782, 8), 256, 0, stream>>>(layer ? (const void*)h1 : x, Wf2, xwb,
                                                sbuf, tbuf,
                                                layer ? flags + 1 : flags, layer);
        k_attn<<<12500, 256, 0, stream>>>(rowptr, elist, ei, et, sbuf, tbuf, xwb,
                                          b, lg, lb,
                                          layer ? h1 : (const u16*)nullptr,
                                          layer ? hsum : h1, flags);
    }
    // decode weight swizzle into xwb space (xwb dead after attn L1)
    k_dswz<<<17, 256, 0, stream>>>(mw1, mw2, Wf, flags);
    k_decode2<<<3125, 256, 0, stream>>>(hsum, edges, Wf, mb1, mb2, d_out, flags);
}

// Round 15
// 491.249 us; speedup vs baseline: 1.2133x; 1.0282x over previous
//
#include <hip/hip_runtime.h>
#include <hip/hip_bf16.h>

#define NN    50000
#define RR    8
#define HIDC  128
#define NHEADS 4
#define EE    640000
#define EE2   200000
#define NCL   8

typedef __hip_bfloat16 bf16;
typedef unsigned short u16;
typedef __attribute__((ext_vector_type(8))) short short8;
typedef __attribute__((ext_vector_type(4))) float floatx4;

__device__ __forceinline__ float us2f(u16 u) {
    return __uint_as_float(((unsigned)u) << 16);
}
__device__ __forceinline__ float bf2f(bf16 v) { return __bfloat162float(v); }
__device__ __forceinline__ u16 f2us(float f) {
    bf16 h = __float2bfloat16(f);
    return *(u16*)&h;
}
__device__ __forceinline__ float ldf(const void* p, int i, bool f32) {
    return f32 ? ((const float*)p)[i] : us2f(((const u16*)p)[i]);
}
__device__ __forceinline__ float wredmax(float v) {
#pragma unroll
    for (int off = 32; off; off >>= 1) v = fmaxf(v, __shfl_xor(v, off));
    return v;
}
__device__ __forceinline__ float wredsum(float v) {
#pragma unroll
    for (int off = 32; off; off >>= 1) v += __shfl_xor(v, off);
    return v;
}

// ---------------- dtype sniff: fp32 data viewed as bf16 has exp==0xFF hits ----------------
__global__ __launch_bounds__(1024) void k_sniff(const u16* __restrict__ x, int* __restrict__ flags) {
    __shared__ int cnt;
    if (threadIdx.x == 0) cnt = 0;
    __syncthreads();
    int c = 0;
#pragma unroll
    for (int it = 0; it < 8; it++) {
        ushort4 a = ((const ushort4*)x)[(it * 1024 + threadIdx.x) * 2];
        ushort4 b = ((const ushort4*)x)[(it * 1024 + threadIdx.x) * 2 + 1];
        c += (((a.x >> 7) & 0xFF) == 0xFF) + (((a.y >> 7) & 0xFF) == 0xFF)
           + (((a.z >> 7) & 0xFF) == 0xFF) + (((a.w >> 7) & 0xFF) == 0xFF)
           + (((b.x >> 7) & 0xFF) == 0xFF) + (((b.y >> 7) & 0xFF) == 0xFF)
           + (((b.z >> 7) & 0xFF) == 0xFF) + (((b.w >> 7) & 0xFF) == 0xFF);
    }
    c += __shfl_xor(c, 32); c += __shfl_xor(c, 16); c += __shfl_xor(c, 8);
    c += __shfl_xor(c, 4);  c += __shfl_xor(c, 2);  c += __shfl_xor(c, 1);
    if ((threadIdx.x & 63) == 0) atomicAdd(&cnt, c);
    __syncthreads();
    if (threadIdx.x == 0) { flags[0] = (cnt > 16) ? 1 : 0; flags[1] = 0; }  // [1]=0: internal bf16
}

// ---------------- CSR build ----------------
__global__ void k_zero(int* __restrict__ p, int n) {
    int i = blockIdx.x * 256 + threadIdx.x;
    if (i < n) p[i] = 0;
}
__global__ void k_hist(const int* __restrict__ ei, int* __restrict__ deg) {
    int e = blockIdx.x * 256 + threadIdx.x;
    if (e < EE) atomicAdd(&deg[ei[EE + e]], 1);
}
// 3-phase parallel scan
__global__ __launch_bounds__(256) void k_scan1(const int* __restrict__ deg,
                                               int* __restrict__ bsum) {
    int i = blockIdx.x * 256 + threadIdx.x;
    int v = (i < NN) ? deg[i] : 0;
    __shared__ int red[4];
    int lane = threadIdx.x & 63, w = threadIdx.x >> 6;
#pragma unroll
    for (int off = 32; off; off >>= 1) v += __shfl_xor(v, off);
    if (lane == 0) red[w] = v;
    __syncthreads();
    if (threadIdx.x == 0) bsum[blockIdx.x] = red[0] + red[1] + red[2] + red[3];
}
__global__ __launch_bounds__(256) void k_scan2(const int* __restrict__ bsum,
                                               int* __restrict__ boff,
                                               int* __restrict__ rowptr) {
    __shared__ int s[256];
    int t = threadIdx.x;
    s[t] = (t < 196) ? bsum[t] : 0;
    __syncthreads();
    for (int off = 1; off < 256; off <<= 1) {
        int u = (t >= off) ? s[t - off] : 0;
        __syncthreads();
        s[t] += u;
        __syncthreads();
    }
    if (t < 196) boff[t] = (t == 0) ? 0 : s[t - 1];
    if (t == 255) rowptr[NN] = s[255];
}
__global__ __launch_bounds__(256) void k_scan3(int* __restrict__ deg /*in deg, out cursor*/,
                                               const int* __restrict__ boff,
                                               int* __restrict__ rowptr) {
    __shared__ int s[256];
    int t = threadIdx.x;
    int i = blockIdx.x * 256 + t;
    int v = (i < NN) ? deg[i] : 0;
    s[t] = v;
    __syncthreads();
    for (int off = 1; off < 256; off <<= 1) {
        int u = (t >= off) ? s[t - off] : 0;
        __syncthreads();
        s[t] += u;
        __syncthreads();
    }
    if (i < NN) {
        int val = boff[blockIdx.x] + s[t] - v;  // exclusive
        rowptr[i] = val;
        deg[i] = val;  // cursor copy
    }
}
__global__ void k_scatter(const int* __restrict__ ei, int* __restrict__ cursor,
                          int* __restrict__ elist) {
    int e = blockIdx.x * 256 + threadIdx.x;
    if (e >= EE) return;
    int pos = atomicAdd(&cursor[ei[EE + e]], 1);
    elist[pos] = e;
}

// ---------------- qkw[mat][i][h8] = sum_o W[r][i][o] * (q|k)[o][h] ----------------
__global__ void k_qkw(const void* __restrict__ w1, const void* __restrict__ w2,
                      const void* __restrict__ q1, const void* __restrict__ k1,
                      const void* __restrict__ q2, const void* __restrict__ k2,
                      float* __restrict__ qkw, const int* __restrict__ fl) {
    int idx = blockIdx.x * 256 + threadIdx.x;  // 16*128*8 = 16384
    if (idx >= 16384) return;
    const bool f = fl[0] != 0;
    int mat = idx >> 10;
    int i   = (idx >> 3) & 127;
    int h8  = idx & 7;
    const void* W = (mat >= 8) ? w2 : w1;
    const void* qk = (mat >= 8) ? ((h8 < 4) ? q2 : k2) : ((h8 < 4) ? q1 : k1);
    int h = h8 & 3;
    int r = mat & 7;
    float acc = 0.f;
    for (int o = 0; o < HIDC; o++)
        acc += ldf(W, (r * HIDC + i) * HIDC + o, f) * ldf(qk, o * NHEADS + h, f);
    qkw[idx] = acc;
}

// ---------------- W (+qkw cols) -> MFMA B-fragment order: 9 col-tiles ----------------
__global__ void k_wswz(const void* __restrict__ w1, const void* __restrict__ w2,
                       const float* __restrict__ qkw,
                       u16* __restrict__ Wf2, const int* __restrict__ fl) {
    int idx = blockIdx.x * 256 + threadIdx.x;  // 16 * 2304 = 36864
    if (idx >= 36864) return;
    const bool f = fl[0] != 0;
    int mat = idx / 2304, rest = idx % 2304;
    int c = rest >> 8, q = (rest >> 6) & 3, ln = rest & 63;
    int k0 = q * 32 + (ln >> 4) * 8;
    int nn = c * 16 + (ln & 15);
    int r = mat & 7;
    u16 o[8];
    if (c < 8) {
        const void* W = (mat >= 8) ? w2 : w1;
#pragma unroll
        for (int j = 0; j < 8; j++)
            o[j] = f2us(ldf(W, (r * HIDC + k0 + j) * HIDC + nn, f));
    } else {
        int col = nn - 128;  // 0..15
#pragma unroll
        for (int j = 0; j < 8; j++)
            o[j] = (col < 8) ? f2us(qkw[mat * 1024 + (k0 + j) * 8 + col]) : (u16)0;
    }
    u16* dst = Wf2 + (size_t)mat * 18432 + (size_t)(((c * 4 + q) * 64 + ln) * 8);
    *(ushort4*)dst       = ushort4{o[0], o[1], o[2], o[3]};
    *(ushort4*)(dst + 4) = ushort4{o[4], o[5], o[6], o[7]};
}

// ---------------- MFMA xw + s/t: one block per 64-node tile, all 8 relations ----------------
// Stage X once; A-fragments invariant across r. Per r: 9 col-tile MFMAs, wave-local
// Os round-trip (no barriers in r-loop), coalesced xw store, s/t from col-tile 8.
__global__ __launch_bounds__(256) void k_xw2(const void* __restrict__ X,
                                             const u16* __restrict__ Wf2,
                                             bf16* __restrict__ xw,
                                             float* __restrict__ sbuf,
                                             float* __restrict__ tbuf,
                                             const int* __restrict__ fx,
                                             int layer) {
    __shared__ u16 Xs[64 * 136];    // 17.4 KB bf16 input tile
    __shared__ float Os[64 * 132];  // 33.8 KB fp32 out tile (wave-partitioned rows)
    const int tid = threadIdx.x;
    const int n0 = blockIdx.x * 64;
    const bool xf = fx[0] != 0;
    for (int v = tid; v < 2048; v += 256) {
        int row = v >> 5, c4 = (v & 31) * 4, n = n0 + row;
        ushort4 o = {0, 0, 0, 0};
        if (n < NN) {
            if (xf) {
                float4 hv = *(const float4*)((const float*)X + (size_t)n * HIDC + c4);
                o = ushort4{f2us(hv.x), f2us(hv.y), f2us(hv.z), f2us(hv.w)};
            } else {
                o = *(const ushort4*)((const u16*)X + (size_t)n * HIDC + c4);
            }
        }
        *(ushort4*)&Xs[row * 136 + c4] = o;
    }
    __syncthreads();
    const int w = tid >> 6, lane = tid & 63;
    short8 af[4];
#pragma unroll
    for (int q = 0; q < 4; q++)
        af[q] = *(const short8*)&Xs[(16 * w + (lane & 15)) * 136 + q * 32 + (lane >> 4) * 8];
    for (int r = 0; r < 8; r++) {
        const u16* Wfr = Wf2 + (size_t)(layer * 8 + r) * 18432;
#pragma unroll
        for (int c = 0; c < 9; c++) {
            floatx4 acc = {0.f, 0.f, 0.f, 0.f};
#pragma unroll
            for (int q = 0; q < 4; q++) {
                short8 bfr = *(const short8*)&Wfr[(size_t)(((c * 4 + q) * 64 + lane) * 8)];
                acc = __builtin_amdgcn_mfma_f32_16x16x32_bf16(af[q], bfr, acc, 0, 0, 0);
            }
            if (c < 8) {
                int col = c * 16 + (lane & 15);
#pragma unroll
                for (int reg = 0; reg < 4; reg++) {
                    int p = 16 * w + (lane >> 4) * 4 + reg;
                    Os[p * 132 + col] = acc[reg];
                }
            } else {
                int cl = lane & 15;  // 0..3 -> s heads, 4..7 -> t heads
                if (cl < 8) {
                    float* dstp = (cl < 4) ? sbuf : tbuf;
                    int h = cl & 3;
#pragma unroll
                    for (int reg = 0; reg < 4; reg++) {
                        int p = 16 * w + (lane >> 4) * 4 + reg;
                        int n = n0 + p;
                        if (n < NN) dstp[(size_t)(n * RR + r) * 4 + h] = acc[reg];
                    }
                }
            }
        }
        // wave-local store: wave w owns Os rows 16w..16w+15 (compiler orders LDS within wave)
#pragma unroll
        for (int i = 0; i < 8; i++) {
            int v = i * 64 + lane;               // 0..511
            int row = 16 * w + (v >> 5);
            int c4 = (v & 31) * 4;
            int n = n0 + row;
            if (n < NN) {
                float4 hv = *(const float4*)&Os[row * 132 + c4];
                ushort4 o = {f2us(hv.x), f2us(hv.y), f2us(hv.z), f2us(hv.w)};
                *(ushort4*)((u16*)xw + (size_t)(n * RR + r) * HIDC + c4) = o;
            }
        }
    }
}

// ---------------- fused attention: 2 edges in flight via wave halves, shuffle-fed ----------------
__global__ __launch_bounds__(256) void k_attn(const int* __restrict__ rowptr,
                                              const int* __restrict__ elist,
                                              const int* __restrict__ ei,
                                              const int* __restrict__ et,
                                              const float* __restrict__ sb,
                                              const float* __restrict__ tb,
                                              const bf16* __restrict__ xw,
                                              const void* __restrict__ b,
                                              const void* __restrict__ g,
                                              const void* __restrict__ bb,
                                              const u16* __restrict__ hprev,
                                              u16* __restrict__ hout,
                                              const int* __restrict__ fl) {
    const int lane = threadIdx.x & 63;
    const int d = blockIdx.x * 4 + (threadIdx.x >> 6);
    if (d >= NN) return;
    const bool f = fl[0] != 0;
    const int half = lane >> 5;
    const int sl = lane & 31;
    const int hh = sl >> 3;
    const int start = rowptr[d], end = rowptr[d + 1];
    float m0 = -1e30f, m1 = -1e30f, m2 = -1e30f, m3 = -1e30f;
    float l0 = 0.f, l1 = 0.f, l2 = 0.f, l3 = 0.f;
    float acc0 = 0.f, acc1 = 0.f, acc2 = 0.f, acc3 = 0.f;
    for (int c0 = start; c0 < end; c0 += 64) {
        int n = end - c0;
        if (n > 64) n = 64;
        float a0, a1, a2, a3;
        int sr = 0;
        if (lane < n) {
            int e = elist[c0 + lane];
            int src = ei[e], r = et[e];
            sr = src * RR + r;
            float4 si = *(const float4*)&sb[(size_t)(d * RR + r) * 4];
            float4 tj = *(const float4*)&tb[(size_t)sr * 4];
            a0 = si.x + tj.x; a0 = a0 >= 0.f ? a0 : 0.2f * a0;
            a1 = si.y + tj.y; a1 = a1 >= 0.f ? a1 : 0.2f * a1;
            a2 = si.z + tj.z; a2 = a2 >= 0.f ? a2 : 0.2f * a2;
            a3 = si.w + tj.w; a3 = a3 >= 0.f ? a3 : 0.2f * a3;
        } else { a0 = a1 = a2 = a3 = -1e30f; }
        float n0 = fmaxf(m0, wredmax(a0));
        float n1 = fmaxf(m1, wredmax(a1));
        float n2 = fmaxf(m2, wredmax(a2));
        float n3 = fmaxf(m3, wredmax(a3));
        float s0 = __expf(m0 - n0), s1 = __expf(m1 - n1);
        float s2 = __expf(m2 - n2), s3 = __expf(m3 - n3);
        float e0 = __expf(a0 - n0), e1 = __expf(a1 - n1);
        float e2 = __expf(a2 - n2), e3 = __expf(a3 - n3);
        l0 = l0 * s0 + wredsum(e0);
        l1 = l1 * s1 + wredsum(e1);
        l2 = l2 * s2 + wredsum(e2);
        l3 = l3 * s3 + wredsum(e3);
        float scl = hh == 0 ? s0 : hh == 1 ? s1 : hh == 2 ? s2 : s3;
        acc0 *= scl; acc1 *= scl; acc2 *= scl; acc3 *= scl;
        for (int j2 = 0; j2 < n; j2 += 2) {
            int jl = j2 + half;
            int srj = __shfl(sr, jl);
            float wx = __shfl(e0, jl), wy = __shfl(e1, jl);
            float wz = __shfl(e2, jl), ww = __shfl(e3, jl);
            float wgt = hh == 0 ? wx : hh == 1 ? wy : hh == 2 ? wz : ww;
            ushort4 u = *(const ushort4*)((const u16*)xw + (size_t)srj * HIDC + sl * 4);
            acc0 += wgt * us2f(u.x);
            acc1 += wgt * us2f(u.y);
            acc2 += wgt * us2f(u.z);
            acc3 += wgt * us2f(u.w);
        }
        m0 = n0; m1 = n1; m2 = n2; m3 = n3;
    }
    acc0 += __shfl_xor(acc0, 32);
    acc1 += __shfl_xor(acc1, 32);
    acc2 += __shfl_xor(acc2, 32);
    acc3 += __shfl_xor(acc3, 32);
    float ld = hh == 0 ? l0 : hh == 1 ? l1 : hh == 2 ? l2 : l3;
    float inv = 1.f / (ld + 1e-16f);
    float v0 = fmaxf(acc0 * inv + ldf(b, sl * 4 + 0, f), 0.f);
    float v1 = fmaxf(acc1 * inv + ldf(b, sl * 4 + 1, f), 0.f);
    float v2 = fmaxf(acc2 * inv + ldf(b, sl * 4 + 2, f), 0.f);
    float v3 = fmaxf(acc3 * inv + ldf(b, sl * 4 + 3, f), 0.f);
    float sum = v0 + v1 + v2 + v3;
#pragma unroll
    for (int off = 16; off; off >>= 1) sum += __shfl_xor(sum, off);
    float mean = sum * (1.f / 128.f);
    v0 -= mean; v1 -= mean; v2 -= mean; v3 -= mean;
    float sq = v0 * v0 + v1 * v1 + v2 * v2 + v3 * v3;
#pragma unroll
    for (int off = 16; off; off >>= 1) sq += __shfl_xor(sq, off);
    float rstd = rsqrtf(sq * (1.f / 128.f) + 1e-5f);
    if (half == 0) {
        float y0 = v0 * rstd * ldf(g, sl * 4 + 0, f) + ldf(bb, sl * 4 + 0, f);
        float y1 = v1 * rstd * ldf(g, sl * 4 + 1, f) + ldf(bb, sl * 4 + 1, f);
        float y2 = v2 * rstd * ldf(g, sl * 4 + 2, f) + ldf(bb, sl * 4 + 2, f);
        float y3 = v3 * rstd * ldf(g, sl * 4 + 3, f) + ldf(bb, sl * 4 + 3, f);
        if (hprev) {
            ushort4 hv = *(const ushort4*)&hprev[(size_t)d * HIDC + sl * 4];
            y0 += us2f(hv.x); y1 += us2f(hv.y); y2 += us2f(hv.z); y3 += us2f(hv.w);
        }
        ushort4 o = {f2us(y0), f2us(y1), f2us(y2), f2us(y3)};
        *(ushort4*)&hout[(size_t)d * HIDC + sl * 4] = o;
    }
}

// ---------------- mw1 + mw2 -> B-fragment order (bf16) for MFMA decode ----------------
__global__ void k_dswz(const void* __restrict__ mw1, const void* __restrict__ mw2,
                       u16* __restrict__ Wf, const int* __restrict__ fl) {
    int idx = blockIdx.x * 256 + threadIdx.x;  // 0..4351
    if (idx >= 4352) return;
    const bool f = fl[0] != 0;
    u16 o[8];
    if (idx < 4096) {
        int c = idx >> 9, q = (idx >> 6) & 7, ln = idx & 63;
        int k0 = q * 32 + (ln >> 4) * 8;
        int nn = c * 16 + (ln & 15);
#pragma unroll
        for (int j = 0; j < 8; j++)
            o[j] = f2us(ldf(mw1, (k0 + j) * HIDC + nn, f));
    } else {
        int fidx = idx - 4096;           // q*64 + lane
        int q = fidx >> 6, ln = fidx & 63;
        int k0 = q * 32 + (ln >> 4) * 8;
        int nn = ln & 15;
#pragma unroll
        for (int j = 0; j < 8; j++)
            o[j] = (nn < 8) ? f2us(ldf(mw2, (k0 + j) * NCL + nn, f)) : (u16)0;
    }
    *(ushort4*)&Wf[idx * 8]     = ushort4{o[0], o[1], o[2], o[3]};
    *(ushort4*)&Wf[idx * 8 + 4] = ushort4{o[4], o[5], o[6], o[7]};
}

// ---------------- decode: barrier-free, direct bf16 A-fragment gathers ----------------
__global__ __launch_bounds__(256) void k_decode2(const u16* __restrict__ h,
                                                 const int* __restrict__ edges,
                                                 const u16* __restrict__ Wf,
                                                 const void* __restrict__ mb1,
                                                 const void* __restrict__ mb2,
                                                 void* __restrict__ out,
                                                 const int* __restrict__ fl) {
    __shared__ u16 zsu[64 * 136];   // 17.4 KB, wave-local rows only
    const int tid = threadIdx.x;
    const bool f = fl[0] != 0;
    const int p0 = blockIdx.x * 64;
    const int w = tid >> 6, lane = tid & 63;
    const int m = 16 * w + (lane & 15);   // row in 64-tile
    const int g = lane >> 4;              // k-group 0..3
    const int na = edges[(size_t)(p0 + m) * 2];
    const int nb = edges[(size_t)(p0 + m) * 2 + 1];
    short8 af[8];
#pragma unroll
    for (int q = 0; q < 8; q++) {
        int k0 = q * 32 + g * 8;          // 0..248
        af[q] = *(const short8*)(h + (size_t)((k0 >> 7) ? nb : na) * HIDC + (k0 & 127));
    }
#pragma unroll
    for (int c = 0; c < 8; c++) {
        floatx4 acc = {0.f, 0.f, 0.f, 0.f};
#pragma unroll
        for (int q = 0; q < 8; q++) {
            short8 bfr = *(const short8*)&Wf[(size_t)(((c * 8 + q) * 64 + lane) * 8)];
            acc = __builtin_amdgcn_mfma_f32_16x16x32_bf16(af[q], bfr, acc, 0, 0, 0);
        }
        int col = c * 16 + (lane & 15);
        float bv = ldf(mb1, col, f);
#pragma unroll
        for (int reg = 0; reg < 4; reg++) {
            int p = 16 * w + (lane >> 4) * 4 + reg;
            float z = acc[reg] + bv;
            zsu[p * 136 + col] = f2us(0.5f * z * (1.f + erff(z * 0.70710678118654752f)));
        }
    }
    // second GEMM: rows wave-local -> no barrier
    floatx4 acc2 = {0.f, 0.f, 0.f, 0.f};
#pragma unroll
    for (int q = 0; q < 4; q++) {
        short8 af2 = *(const short8*)&zsu[m * 136 + q * 32 + g * 8];
        short8 bfr2 = *(const short8*)&Wf[32768 + (size_t)((q * 64 + lane) * 8)];
        acc2 = __builtin_amdgcn_mfma_f32_16x16x32_bf16(af2, bfr2, acc2, 0, 0, 0);
    }
    int col16 = lane & 15;
    if (col16 < 8) {
        float bv2 = ldf(mb2, col16, f);
#pragma unroll
        for (int reg = 0; reg < 4; reg++) {
            int p = 16 * w + (lane >> 4) * 4 + reg;
            float sv = acc2[reg] + bv2;
            size_t oi = (size_t)(p0 + p) * NCL + col16;
            if (f) ((float*)out)[oi] = sv;
            else   ((bf16*)out)[oi] = __float2bfloat16(sv);
        }
    }
}

extern "C" void kernel_launch(void* const* d_in, const int* in_sizes, int n_in,
                              void* d_out, int out_size, void* d_ws, size_t ws_size,
                              hipStream_t stream) {
    (void)in_sizes; (void)n_in; (void)out_size; (void)ws_size;
    const void* x    = d_in[0];
    const int* ei    = (const int*)d_in[1];
    const int* et    = (const int*)d_in[2];
    const int* edges = (const int*)d_in[3];
    const void* w1 = d_in[4];
    const void* q1 = d_in[5];
    const void* k1 = d_in[6];
    const void* b1 = d_in[7];
    const void* w2 = d_in[8];
    const void* q2 = d_in[9];
    const void* k2 = d_in[10];
    const void* b2 = d_in[11];
    const void* ln1g = d_in[12];
    const void* ln1b = d_in[13];
    const void* ln2g = d_in[14];
    const void* ln2b = d_in[15];
    const void* mw1 = d_in[16];
    const void* mb1 = d_in[17];
    const void* mw2 = d_in[18];
    const void* mb2 = d_in[19];

    // workspace layout — within round-3-proven bound (<= 169,425,560 B)
    char* ws = (char*)d_ws;
    bf16* xwb   = (bf16*)ws;                      // [0, 102,400,000)
    u16* Wf     = (u16*)ws;                       // ALIAS xwb: k_dswz runs after last xwb read (69,632 B)
    float* sbuf = (float*)(ws + 102400000);       // 6.4 MB
    float* tbuf = (float*)(ws + 108800000);       // 6.4 MB
    u16* h1     = (u16*)(ws + 115200000);         // 12.8 MB (bf16)
    u16* hsum   = (u16*)(ws + 140800000);         // 12.8 MB (bf16)
    u16* Wf2    = (u16*)(ws + 153600000);         // 589,824 B
    int* rowptr = (int*)(ws + 166400000);         // NN+1 ints
    int* cursor = (int*)(ws + 166600016);         // NN ints
    int* elist  = (int*)(ws + 166800016);         // EE ints
    float* qkw  = (float*)(ws + 169360016);       // 65,536 B -> ends 169,425,552
    int* bsum   = (int*)qkw;                      // ALIAS qkw: scan phases finish before k_qkw writes
    int* boff   = bsum + 256;
    int* flags  = (int*)(ws + 169425552);         // 8 B -> ends 169,425,560 (proven)

    k_sniff<<<1, 1024, 0, stream>>>((const u16*)x, flags);

    // CSR build (parallel 3-phase scan) + weight preprocessing
    k_zero<<<196, 256, 0, stream>>>(cursor, NN);
    k_hist<<<2500, 256, 0, stream>>>(ei, cursor);
    k_scan1<<<196, 256, 0, stream>>>(cursor, bsum);
    k_scan2<<<1, 256, 0, stream>>>(bsum, boff, rowptr);
    k_scan3<<<196, 256, 0, stream>>>(cursor, boff, rowptr);
    k_scatter<<<2500, 256, 0, stream>>>(ei, cursor, elist);
    k_qkw<<<64, 256, 0, stream>>>(w1, w2, q1, k1, q2, k2, qkw, flags);
    k_wswz<<<144, 256, 0, stream>>>(w1, w2, qkw, Wf2, flags);

    for (int layer = 0; layer < 2; ++layer) {
        const void* b  = layer ? b2 : b1;
        const void* lg = layer ? ln2g : ln1g;
        const void* lb = layer ? ln2b : ln1b;
        k_xw2<<<782, 256, 0, stream>>>(layer ? (const void*)h1 : x, Wf2, xwb,
                                       sbuf, tbuf,
                                       layer ? flags + 1 : flags, layer);
        k_attn<<<12500, 256, 0, stream>>>(rowptr, elist, ei, et, sbuf, tbuf, xwb,
                                          b, lg, lb,
                                          layer ? h1 : (const u16*)nullptr,
                                          layer ? hsum : h1, flags);
    }
    // decode weight swizzle into xwb space (xwb dead after attn L1)
    k_dswz<<<17, 256, 0, stream>>>(mw1, mw2, Wf, flags);
    k_decode2<<<3125, 256, 0, stream>>>(hsum, edges, Wf, mb1, mb2, d_out, flags);
}